// Round 1
// 4642.187 us; speedup vs baseline: 1.7034x; 1.7034x over previous
//
#include <hip/hip_runtime.h>
#include <stdint.h>

typedef unsigned short ushort_t;
typedef unsigned int uint32;

// ---------- sizes (fixed by the problem) ----------
#define NT 20000
#define NC 200000
#define NF 40000
#define E_HC 200000
#define E_BT 200000
#define E_IS 80000
#define E_PT 80000
#define FDIM 256   // H*D
#define NHEAD 4
#define DHEAD 64

// ---------- helpers ----------
__device__ __forceinline__ float blo(uint32 u) { return __uint_as_float(u << 16); }
__device__ __forceinline__ float bhi(uint32 u) { return __uint_as_float(u & 0xFFFF0000u); }
__device__ __forceinline__ ushort_t f2b_raw(float f) {
    unsigned u = __float_as_uint(f);
    unsigned r = u + 0x7fffu + ((u >> 16) & 1u);   // RNE
    return (ushort_t)(r >> 16);
}
__device__ __forceinline__ float finclamp(float v) {
    // NaN -> -1e30 (finite); +-inf -> +-1e30. No-op for sane values.
    return fminf(fmaxf(v, -1e30f), 1e30f);
}

// ---------- GEMM: C[M,N] = act(A[M,K] @ W[K,N] + bias[N]) ----------
// AT: 0 = A is fp32, 1 = A is bf16(raw ushort). W, bias always fp32.
// CT: 0 = C is fp32, 1 = C is bf16(raw ushort). fp32 accumulate.
// BM=128, BN=64, BK=16; 256 threads; each thread computes 8x4.
// act: 0 = none, 1 = leaky_relu(0.01)
#define BM 128
#define BN 64
#define BK 16
template<int AT, int CT>
__global__ __launch_bounds__(256) void gemm_k(
    const void* __restrict__ Av, const float* __restrict__ W,
    const float* __restrict__ bias, void* __restrict__ Cv,
    int M, int N, int K, int act)
{
    __shared__ float As[BK][BM + 1];
    __shared__ float Ws[BK][BN + 1];
    const int t  = threadIdx.x;
    const int m0 = blockIdx.x * BM;
    const int n0 = blockIdx.y * BN;
    const int tx = t & 15, ty = t >> 4;
    const int am = t >> 1;           // 0..127
    const int ak = (t & 1) * 8;      // 0 or 8
    const int wk = t >> 4;           // 0..15
    const int wn = (t & 15) * 4;     // 0..60

    float acc[8][4];
#pragma unroll
    for (int i = 0; i < 8; i++)
#pragma unroll
        for (int j = 0; j < 4; j++) acc[i][j] = 0.f;

    for (int k0 = 0; k0 < K; k0 += BK) {
        // stage A tile [BM x BK] -> As[k][m]; 8 consecutive elems per thread.
        {
            float vals[8];
            int arow = m0 + am;
            if (arow < M) {
                if (AT == 0) {
                    const float* A = (const float*)Av;
                    const float4* p = reinterpret_cast<const float4*>(
                        A + (size_t)arow * K + k0 + ak);   // 32B aligned
                    float4 q0 = p[0], q1 = p[1];
                    vals[0] = q0.x; vals[1] = q0.y; vals[2] = q0.z; vals[3] = q0.w;
                    vals[4] = q1.x; vals[5] = q1.y; vals[6] = q1.z; vals[7] = q1.w;
                } else {
                    const ushort_t* A = (const ushort_t*)Av;
                    uint4 q = *reinterpret_cast<const uint4*>(
                        A + (size_t)arow * K + k0 + ak);   // 16B aligned
                    vals[0] = blo(q.x); vals[1] = bhi(q.x);
                    vals[2] = blo(q.y); vals[3] = bhi(q.y);
                    vals[4] = blo(q.z); vals[5] = bhi(q.z);
                    vals[6] = blo(q.w); vals[7] = bhi(q.w);
                }
            } else {
#pragma unroll
                for (int i = 0; i < 8; i++) vals[i] = 0.f;
            }
#pragma unroll
            for (int i = 0; i < 8; i++) As[ak + i][am] = vals[i];
        }
        // stage W tile [BK x BN] -> Ws[k][n]  (fp32, 16B-aligned float4)
        {
            float4 q = *reinterpret_cast<const float4*>(
                W + (size_t)(k0 + wk) * N + n0 + wn);
            Ws[wk][wn + 0] = q.x;
            Ws[wk][wn + 1] = q.y;
            Ws[wk][wn + 2] = q.z;
            Ws[wk][wn + 3] = q.w;
        }
        __syncthreads();
#pragma unroll
        for (int kk = 0; kk < BK; ++kk) {
            float a[8], w[4];
#pragma unroll
            for (int i = 0; i < 8; i++) a[i] = As[kk][ty * 8 + i];
#pragma unroll
            for (int j = 0; j < 4; j++) w[j] = Ws[kk][tx * 4 + j];
#pragma unroll
            for (int i = 0; i < 8; i++)
#pragma unroll
                for (int j = 0; j < 4; j++) acc[i][j] += a[i] * w[j];
        }
        __syncthreads();
    }

    float bv[4] = {0.f, 0.f, 0.f, 0.f};
    if (bias) {
#pragma unroll
        for (int j = 0; j < 4; j++) bv[j] = bias[n0 + tx * 4 + j];
    }
#pragma unroll
    for (int i = 0; i < 8; i++) {
        int r = m0 + ty * 8 + i;
        if (r >= M) continue;
        size_t base = (size_t)r * N + n0 + tx * 4;
        float v[4];
#pragma unroll
        for (int j = 0; j < 4; j++) {
            float x = acc[i][j] + bv[j];
            if (act == 1) x = (x > 0.f) ? x : 0.01f * x;
            v[j] = finclamp(x);
        }
        if (CT == 0) {
            float* C = (float*)Cv;
            *reinterpret_cast<float4*>(C + base) = make_float4(v[0], v[1], v[2], v[3]);
        } else {
            ushort_t* C = (ushort_t*)Cv;
            uint32 lo = ((uint32)f2b_raw(v[1]) << 16) | (uint32)f2b_raw(v[0]);
            uint32 hi = ((uint32)f2b_raw(v[3]) << 16) | (uint32)f2b_raw(v[2]);
            *reinterpret_cast<uint2*>(C + base) = make_uint2(lo, hi);
        }
    }
}

// ---------- init kernels ----------
__global__ void fill_bias_k(float* __restrict__ o, const float* __restrict__ b1,
                            const float* __restrict__ b2, int n) {
    int i = blockIdx.x * 256 + threadIdx.x;
    if (i >= n) return;
    int f = i & 255;
    float v = b1[f];
    if (b2) v += b2[f];
    o[i] = v;
}

// ---------- CSR build: counting sort of edges by dst ----------
__global__ void zero2_k(int* __restrict__ a, int* __restrict__ b, int n) {
    int i = blockIdx.x * 256 + threadIdx.x;
    if (i < n) { a[i] = 0; b[i] = 0; }
}

__global__ void hist_k(const int* __restrict__ dst, int* __restrict__ cnt, int E) {
    int e = blockIdx.x * 256 + threadIdx.x;
    if (e < E) atomicAdd(&cnt[dst[e]], 1);
}

// single-workgroup exclusive scan of cnt[0..n) -> off[0..n], off[n] = total.
// 1024 threads, 4 elems/thread/chunk, wave shuffle scan + LDS cross-wave.
__global__ __launch_bounds__(1024) void scan_k(const int* __restrict__ cnt,
                                               int* __restrict__ off, int n) {
    __shared__ int wsum[16];
    __shared__ int cbase;
    int t = threadIdx.x, lane = t & 63, w = t >> 6;
    if (t == 0) cbase = 0;
    __syncthreads();
    for (int s0 = 0; s0 < n; s0 += 4096) {
        int i = s0 + t * 4;
        int v[4];
#pragma unroll
        for (int k = 0; k < 4; k++) v[k] = (i + k < n) ? cnt[i + k] : 0;
        int ts = v[0] + v[1] + v[2] + v[3];
        int x = ts;
#pragma unroll
        for (int sh = 1; sh < 64; sh <<= 1) {
            int y = __shfl_up(x, sh);
            if (lane >= sh) x += y;
        }
        if (lane == 63) wsum[w] = x;
        int base_read = cbase;
        __syncthreads();
        int wbase = 0;
        for (int k = 0; k < w; k++) wbase += wsum[k];
        int excl = base_read + wbase + (x - ts);
#pragma unroll
        for (int k = 0; k < 4; k++) {
            if (i + k < n) off[i + k] = excl;
            excl += v[k];
        }
        __syncthreads();
        if (t == 0) {
            int tot = 0;
            for (int k = 0; k < 16; k++) tot += wsum[k];
            cbase += tot;
        }
        __syncthreads();
    }
    if (threadIdx.x == 0) off[n] = cbase;
}

// scatter src ids into dst-sorted order (within-node order arbitrary)
__global__ void permsrc_k(const int* __restrict__ dst, const int* __restrict__ src,
                          const int* __restrict__ off, int* __restrict__ cur,
                          int* __restrict__ ssrc, int E) {
    int e = blockIdx.x * 256 + threadIdx.x;
    if (e >= E) return;
    int d = dst[e];
    int slot = atomicAdd(&cur[d], 1);
    ssrc[off[d] + slot] = src[e];
}

// ---------- fused GATv2 gather: one wave per dst node, online softmax ----------
// Replaces init_md / edge_logits / edge_z / edge_scatter. No atomics.
// lane handles features f = lane*4 .. lane*4+3; head h = lane>>4.
__global__ __launch_bounds__(256) void gat_gather_k(
    const ushort_t* __restrict__ xl, const ushort_t* __restrict__ xr,
    const float* __restrict__ att, const int* __restrict__ off,
    const int* __restrict__ ssrc, float* __restrict__ out, int Nd)
{
    int d = blockIdx.x * 4 + (threadIdx.x >> 6);
    if (d >= Nd) return;
    int j0 = off[d], j1 = off[d + 1];
    if (j0 == j1) return;           // zero in-degree: out keeps its bias fill
    int lane = threadIdx.x & 63;
    int f = lane * 4;
    float4 qa = *reinterpret_cast<const float4*>(att + f);
    uint2 qr = *reinterpret_cast<const uint2*>(xr + (size_t)d * FDIM + f);
    float r0 = blo(qr.x), r1 = bhi(qr.x), r2 = blo(qr.y), r3 = bhi(qr.y);

    float m = -1e30f, den = 0.f;
    float a0 = 0.f, a1 = 0.f, a2 = 0.f, a3 = 0.f;
    for (int j = j0; j < j1; ++j) {
        int s = ssrc[j];
        uint2 ql = *reinterpret_cast<const uint2*>(xl + (size_t)s * FDIM + f);
        float l0 = blo(ql.x), l1 = bhi(ql.x), l2 = blo(ql.y), l3 = bhi(ql.y);
        float v0 = l0 + r0, v1 = l1 + r1, v2 = l2 + r2, v3 = l3 + r3;
        v0 = (v0 > 0.f) ? v0 : 0.2f * v0;
        v1 = (v1 > 0.f) ? v1 : 0.2f * v1;
        v2 = (v2 > 0.f) ? v2 : 0.2f * v2;
        v3 = (v3 > 0.f) ? v3 : 0.2f * v3;
        float lg = qa.x * v0 + qa.y * v1 + qa.z * v2 + qa.w * v3;
        // reduce within the 16-lane head group -> full 64-dim dot per head
        lg += __shfl_xor(lg, 1);
        lg += __shfl_xor(lg, 2);
        lg += __shfl_xor(lg, 4);
        lg += __shfl_xor(lg, 8);
        // online softmax update (per head; replicated across the 16 lanes)
        float mn = fmaxf(m, lg);
        float sc = expf(m - mn);     // first edge: exp(-huge) underflows to 0
        float z  = expf(lg - mn);
        den = den * sc + z;
        a0 = a0 * sc + z * l0;
        a1 = a1 * sc + z * l1;
        a2 = a2 * sc + z * l2;
        a3 = a3 * sc + z * l3;
        m = mn;
    }
    float inv = (den > 0.f) ? 1.f / den : 0.f;
    float* op = out + (size_t)d * FDIM + f;
    float4 o = *reinterpret_cast<float4*>(op);
    o.x += finclamp(a0 * inv);
    o.y += finclamp(a1 * inv);
    o.z += finclamp(a2 * inv);
    o.w += finclamp(a3 * inv);
    *reinterpret_cast<float4*>(op) = o;
}

// ---------- combine: x = elu(scale * o) -> bf16 ----------
__global__ void combine_elu_k(const float* __restrict__ o, ushort_t* __restrict__ x,
                              float scale, int n)
{
    int i = blockIdx.x * 256 + threadIdx.x;
    if (i >= n) return;
    float v = scale * o[i];
    v = (v > 0.f) ? v : (expf(v) - 1.f);
    x[i] = f2b_raw(finclamp(v));
}

// ---------- host launch ----------
extern "C" void kernel_launch(void* const* d_in, const int* in_sizes, int n_in,
                              void* d_out, int out_size, void* d_ws, size_t ws_size,
                              hipStream_t stream) {
    (void)in_sizes; (void)n_in; (void)out_size;
    const float* x_table = (const float*)d_in[0];
    const float* x_column = (const float*)d_in[1];
    const float* x_fk = (const float*)d_in[2];
    const float* lin_w = (const float*)d_in[3];   // [3,256,64]
    const float* lin_b = (const float*)d_in[4];   // [3,64]
    const float* out_w = (const float*)d_in[5];   // [3,256,256]
    const float* out_b = (const float*)d_in[6];   // [3,256]
    const float* Wl0 = (const float*)d_in[7];     // [4,64,256]
    const float* Wr0 = (const float*)d_in[8];
    const float* att0 = (const float*)d_in[9];    // [4,4,64]
    const float* b0 = (const float*)d_in[10];     // [4,256]
    const float* Wl1 = (const float*)d_in[11];    // [4,256,256]
    const float* Wr1 = (const float*)d_in[12];
    const float* att1 = (const float*)d_in[13];
    const float* b1 = (const float*)d_in[14];
    const int* src_hc = (const int*)d_in[15];
    const int* dst_hc = (const int*)d_in[16];
    const int* src_bt = (const int*)d_in[17];
    const int* dst_bt = (const int*)d_in[18];
    const int* src_is = (const int*)d_in[19];
    const int* dst_is = (const int*)d_in[20];
    const int* src_pt = (const int*)d_in[21];
    const int* dst_pt = (const int*)d_in[22];
    float* out = (float*)d_out;

    // ---- carve workspace ----
    char* p = (char*)d_ws;
    auto alloc = [&](size_t bytes) -> char* {
        char* r = p;
        p += (bytes + 255) & ~(size_t)255;
        return r;
    };
    ushort_t* xt = (ushort_t*)alloc((size_t)NT * FDIM * 2);
    ushort_t* xc = (ushort_t*)alloc((size_t)NC * FDIM * 2);
    ushort_t* xf = (ushort_t*)alloc((size_t)NF * FDIM * 2);
    ushort_t* xl = (ushort_t*)alloc((size_t)NC * FDIM * 2);
    ushort_t* xr = (ushort_t*)alloc((size_t)NC * FDIM * 2);
    float* o_c = (float*)alloc((size_t)NC * FDIM * 4);
    float* o_t = (float*)alloc((size_t)NT * FDIM * 4);
    float* o_f = (float*)alloc((size_t)NF * FDIM * 4);
    int* off_hc = (int*)alloc((size_t)(NC + 1) * 4);
    int* off_bt = (int*)alloc((size_t)(NT + 1) * 4);
    int* off_is = (int*)alloc((size_t)(NF + 1) * 4);
    int* off_pt = (int*)alloc((size_t)(NC + 1) * 4);
    int* ssrc_hc = (int*)alloc((size_t)E_HC * 4);
    int* ssrc_bt = (int*)alloc((size_t)E_BT * 4);
    int* ssrc_is = (int*)alloc((size_t)E_IS * 4);
    int* ssrc_pt = (int*)alloc((size_t)E_PT * 4);
    int* cnt = (int*)alloc((size_t)NC * 4);
    int* cur = (int*)alloc((size_t)NC * 4);
    if ((size_t)(p - (char*)d_ws) > ws_size) return;

    auto grid_for = [&](int M, int N) { return dim3((M + BM - 1) / BM, N / BN); };
    auto gemm_fb = [&](const float* A, const float* W, const float* bias,
                       ushort_t* C, int M, int N, int K, int act) {
        hipLaunchKernelGGL((gemm_k<0, 1>), grid_for(M, N), dim3(256), 0, stream,
                           (const void*)A, W, bias, (void*)C, M, N, K, act);
    };
    auto gemm_bb = [&](const ushort_t* A, const float* W, const float* bias,
                       ushort_t* C, int M, int N, int K, int act) {
        hipLaunchKernelGGL((gemm_k<1, 1>), grid_for(M, N), dim3(256), 0, stream,
                           (const void*)A, W, bias, (void*)C, M, N, K, act);
    };
    auto gemm_bf = [&](const ushort_t* A, const float* W, const float* bias,
                       float* C, int M, int N, int K, int act) {
        hipLaunchKernelGGL((gemm_k<1, 0>), grid_for(M, N), dim3(256), 0, stream,
                           (const void*)A, W, bias, (void*)C, M, N, K, act);
    };

    // ---- CSR build (once; reused by both layers) ----
    auto build_csr = [&](const int* dst, const int* src, int E, int Nd,
                         int* off, int* ssrc) {
        hipLaunchKernelGGL(zero2_k, dim3((Nd + 255) / 256), dim3(256), 0, stream,
                           cnt, cur, Nd);
        hipLaunchKernelGGL(hist_k, dim3((E + 255) / 256), dim3(256), 0, stream,
                           dst, cnt, E);
        hipLaunchKernelGGL(scan_k, dim3(1), dim3(1024), 0, stream, cnt, off, Nd);
        hipLaunchKernelGGL(permsrc_k, dim3((E + 255) / 256), dim3(256), 0, stream,
                           dst, src, off, cur, ssrc, E);
    };
    build_csr(dst_hc, src_hc, E_HC, NC, off_hc, ssrc_hc);
    build_csr(dst_bt, src_bt, E_BT, NT, off_bt, ssrc_bt);
    build_csr(dst_is, src_is, E_IS, NF, off_is, ssrc_is);
    build_csr(dst_pt, src_pt, E_PT, NC, off_pt, ssrc_pt);

    // ---- input projections: [N,256] @ [256,64] + b, leaky 0.01 ----
    gemm_fb(x_table, lin_w + 0 * 256 * 64, lin_b + 0 * 64, xt, NT, 64, 256, 1);
    gemm_fb(x_column, lin_w + 1 * 256 * 64, lin_b + 1 * 64, xc, NC, 64, 256, 1);
    gemm_fb(x_fk, lin_w + 2 * 256 * 64, lin_b + 2 * 64, xf, NF, 64, 256, 1);

    auto run_edge_type = [&](const ushort_t* xsrc, int Ns, const ushort_t* xdst, int Nd,
                             const int* off, const int* ssrc,
                             const float* Wl_t, const float* Wr_t,
                             const float* att_t, float* obuf, int Kd) {
        gemm_bb(xsrc, Wl_t, nullptr, xl, Ns, FDIM, Kd, 0);
        gemm_bb(xdst, Wr_t, nullptr, xr, Nd, FDIM, Kd, 0);
        hipLaunchKernelGGL(gat_gather_k, dim3((Nd + 3) / 4), dim3(256), 0, stream,
                           xl, xr, att_t, off, ssrc, obuf, Nd);
    };

    for (int l = 0; l < 2; l++) {
        const float* Wl = l ? Wl1 : Wl0;
        const float* Wr = l ? Wr1 : Wr0;
        const float* att = l ? att1 : att0;
        const float* bb = l ? b1 : b0;
        int Kd = l ? 256 : 64;
        size_t wstep = (size_t)Kd * FDIM;

        hipLaunchKernelGGL(fill_bias_k, dim3((NT * FDIM + 255) / 256), dim3(256), 0, stream,
                           o_t, bb + 1 * FDIM, (const float*)nullptr, NT * FDIM);
        hipLaunchKernelGGL(fill_bias_k, dim3((NF * FDIM + 255) / 256), dim3(256), 0, stream,
                           o_f, bb + 2 * FDIM, (const float*)nullptr, NF * FDIM);
        hipLaunchKernelGGL(fill_bias_k, dim3((NC * FDIM + 255) / 256), dim3(256), 0, stream,
                           o_c, bb + 0 * FDIM, bb + 3 * FDIM, NC * FDIM);

        run_edge_type(xt, NT, xc, NC, off_hc, ssrc_hc,
                      Wl + 0 * wstep, Wr + 0 * wstep, att + 0 * FDIM, o_c, Kd);
        run_edge_type(xc, NC, xt, NT, off_bt, ssrc_bt,
                      Wl + 1 * wstep, Wr + 1 * wstep, att + 1 * FDIM, o_t, Kd);
        run_edge_type(xc, NC, xf, NF, off_is, ssrc_is,
                      Wl + 2 * wstep, Wr + 2 * wstep, att + 2 * FDIM, o_f, Kd);
        run_edge_type(xf, NF, xc, NC, off_pt, ssrc_pt,
                      Wl + 3 * wstep, Wr + 3 * wstep, att + 3 * FDIM, o_c, Kd);

        hipLaunchKernelGGL(combine_elu_k, dim3((NT * FDIM + 255) / 256), dim3(256), 0, stream,
                           o_t, xt, 1.0f, NT * FDIM);
        hipLaunchKernelGGL(combine_elu_k, dim3((NC * FDIM + 255) / 256), dim3(256), 0, stream,
                           o_c, xc, 0.5f, NC * FDIM);
        hipLaunchKernelGGL(combine_elu_k, dim3((NF * FDIM + 255) / 256), dim3(256), 0, stream,
                           o_f, xf, 1.0f, NF * FDIM);
    }

    // ---- output projections -> d_out (concat xt, xc, xf), fp32 ----
    gemm_bf(xt, out_w + 0 * 256 * 256, out_b + 0 * 256, out, NT, 256, 256, 0);
    gemm_bf(xc, out_w + 1 * 256 * 256, out_b + 1 * 256, out + (size_t)NT * FDIM, NC, 256, 256, 0);
    gemm_bf(xf, out_w + 2 * 256 * 256, out_b + 2 * 256, out + (size_t)(NT + NC) * FDIM, NF, 256, 256, 0);
}

// Round 2
// 2656.697 us; speedup vs baseline: 2.9764x; 1.7474x over previous
//
#include <hip/hip_runtime.h>
#include <stdint.h>

typedef unsigned short ushort_t;
typedef unsigned int uint32;

// ---------- sizes (fixed by the problem) ----------
#define NT 20000
#define NC 200000
#define NF 40000
#define E_HC 200000
#define E_BT 200000
#define E_IS 80000
#define E_PT 80000
#define FDIM 256   // H*D
#define NHEAD 4
#define DHEAD 64

typedef __attribute__((ext_vector_type(8))) short short8;
typedef __attribute__((ext_vector_type(4))) float f32x4;

// ---------- helpers ----------
__device__ __forceinline__ float blo(uint32 u) { return __uint_as_float(u << 16); }
__device__ __forceinline__ float bhi(uint32 u) { return __uint_as_float(u & 0xFFFF0000u); }
__device__ __forceinline__ ushort_t f2b_raw(float f) {
    unsigned u = __float_as_uint(f);
    unsigned r = u + 0x7fffu + ((u >> 16) & 1u);   // RNE
    return (ushort_t)(r >> 16);
}
__device__ __forceinline__ float finclamp(float v) {
    // NaN -> -1e30 (finite); +-inf -> +-1e30. No-op for sane values.
    return fminf(fmaxf(v, -1e30f), 1e30f);
}

// ---------- VALU GEMM (kept for fp32-input projections, N=64) ----------
// C[M,N] = act(A[M,K] @ W[K,N] + bias[N]); A fp32, C bf16. BM=128,BN=64,BK=16.
#define BM 128
#define BN 64
#define BK 16
__global__ __launch_bounds__(256) void gemm_k(
    const float* __restrict__ A, const float* __restrict__ W,
    const float* __restrict__ bias, ushort_t* __restrict__ C,
    int M, int N, int K, int act)
{
    __shared__ float As[BK][BM + 1];
    __shared__ float Ws[BK][BN + 1];
    const int t  = threadIdx.x;
    const int m0 = blockIdx.x * BM;
    const int n0 = blockIdx.y * BN;
    const int tx = t & 15, ty = t >> 4;
    const int am = t >> 1;           // 0..127
    const int ak = (t & 1) * 8;      // 0 or 8
    const int wk = t >> 4;           // 0..15
    const int wn = (t & 15) * 4;     // 0..60

    float acc[8][4];
#pragma unroll
    for (int i = 0; i < 8; i++)
#pragma unroll
        for (int j = 0; j < 4; j++) acc[i][j] = 0.f;

    for (int k0 = 0; k0 < K; k0 += BK) {
        {
            float vals[8];
            int arow = m0 + am;
            if (arow < M) {
                const float4* p = reinterpret_cast<const float4*>(
                    A + (size_t)arow * K + k0 + ak);
                float4 q0 = p[0], q1 = p[1];
                vals[0] = q0.x; vals[1] = q0.y; vals[2] = q0.z; vals[3] = q0.w;
                vals[4] = q1.x; vals[5] = q1.y; vals[6] = q1.z; vals[7] = q1.w;
            } else {
#pragma unroll
                for (int i = 0; i < 8; i++) vals[i] = 0.f;
            }
#pragma unroll
            for (int i = 0; i < 8; i++) As[ak + i][am] = vals[i];
        }
        {
            float4 q = *reinterpret_cast<const float4*>(
                W + (size_t)(k0 + wk) * N + n0 + wn);
            Ws[wk][wn + 0] = q.x;
            Ws[wk][wn + 1] = q.y;
            Ws[wk][wn + 2] = q.z;
            Ws[wk][wn + 3] = q.w;
        }
        __syncthreads();
#pragma unroll
        for (int kk = 0; kk < BK; ++kk) {
            float a[8], w[4];
#pragma unroll
            for (int i = 0; i < 8; i++) a[i] = As[kk][ty * 8 + i];
#pragma unroll
            for (int j = 0; j < 4; j++) w[j] = Ws[kk][tx * 4 + j];
#pragma unroll
            for (int i = 0; i < 8; i++)
#pragma unroll
                for (int j = 0; j < 4; j++) acc[i][j] += a[i] * w[j];
        }
        __syncthreads();
    }

    float bv[4] = {0.f, 0.f, 0.f, 0.f};
    if (bias) {
#pragma unroll
        for (int j = 0; j < 4; j++) bv[j] = bias[n0 + tx * 4 + j];
    }
#pragma unroll
    for (int i = 0; i < 8; i++) {
        int r = m0 + ty * 8 + i;
        if (r >= M) continue;
        size_t base = (size_t)r * N + n0 + tx * 4;
        float v[4];
#pragma unroll
        for (int j = 0; j < 4; j++) {
            float x = acc[i][j] + bv[j];
            if (act == 1) x = (x > 0.f) ? x : 0.01f * x;
            v[j] = finclamp(x);
        }
        uint32 lo = ((uint32)f2b_raw(v[1]) << 16) | (uint32)f2b_raw(v[0]);
        uint32 hi = ((uint32)f2b_raw(v[3]) << 16) | (uint32)f2b_raw(v[2]);
        *reinterpret_cast<uint2*>(C + base) = make_uint2(lo, hi);
    }
}

// ---------- weight split: W[K][256] fp32 -> Wt_hi/Wt_lo [256][K] bf16 ----------
// hi = bf16(w); lo = bf16(w - hi). A@(hi+lo) ~= fp32-exact weights (2^-17 rel).
__global__ void wsplit_k(const float* __restrict__ W, ushort_t* __restrict__ Wh,
                         ushort_t* __restrict__ Wl, int K) {
    int i = blockIdx.x * 256 + threadIdx.x;
    if (i >= K * 256) return;
    int k = i >> 8, n = i & 255;
    float w = W[i];
    ushort_t h = f2b_raw(w);
    float hf = __uint_as_float((uint32)h << 16);
    ushort_t l = f2b_raw(w - hf);
    Wh[(size_t)n * K + k] = h;
    Wl[(size_t)n * K + k] = l;
}

// ---------- MFMA GEMM: C[M,256] = A[M,K](bf16) @ W(hi+lo) + bias ----------
// BMm=128, BNm=128, BKm=32; 4 waves in 2x2, each 64x64 via 4x4 16x16 frags.
// Two MFMAs (hi,lo) per fragment into one fp32 acc. CT: 0=f32 out, 1=bf16 out.
// LDS tiles [128 rows][32 bf16], 16B-slot XOR swizzle: slot ^= (row>>1)&3
// -> frag ds_read_b128 is 2-way bank aliasing max (free).
template<int CT>
__global__ __launch_bounds__(256) void gemm_mfma_k(
    const ushort_t* __restrict__ A, const ushort_t* __restrict__ Wh,
    const ushort_t* __restrict__ Wl, const float* __restrict__ bias,
    void* __restrict__ Cv, int M, int N, int K)
{
    __shared__ __align__(16) ushort_t As[128][32];
    __shared__ __align__(16) ushort_t Bh[128][32];
    __shared__ __align__(16) ushort_t Bl[128][32];
    const int t = threadIdx.x;
    const int lane = t & 63;
    const int w = t >> 6;
    const int wr = (w >> 1) * 64, wc = (w & 1) * 64;
    const int m0 = blockIdx.x * 128;
    const int n0 = blockIdx.y * 128;
    const int lm = lane & 15, g = lane >> 4;

    f32x4 acc[4][4];
#pragma unroll
    for (int mi = 0; mi < 4; mi++)
#pragma unroll
        for (int ni = 0; ni < 4; ni++) acc[mi][ni] = (f32x4){0.f, 0.f, 0.f, 0.f};

    const int sr = t >> 1;          // staging row 0..127
    const int ss = (t & 1) * 2;     // slots {0,1} or {2,3}
    const int sw = (sr >> 1) & 3;   // swizzle for this staging row

    for (int k0 = 0; k0 < K; k0 += 32) {
        // stage A tile (rows m0+sr)
        {
            int row = m0 + sr;
            uint4 q0 = make_uint4(0u, 0u, 0u, 0u), q1 = q0;
            if (row < M) {
                const uint4* p = reinterpret_cast<const uint4*>(
                    A + (size_t)row * K + k0 + ss * 8);
                q0 = p[0]; q1 = p[1];
            }
            *reinterpret_cast<uint4*>(&As[sr][((ss + 0) ^ sw) * 8]) = q0;
            *reinterpret_cast<uint4*>(&As[sr][((ss + 1) ^ sw) * 8]) = q1;
        }
        // stage B hi/lo tiles (Wt rows n0+sr; N is always a multiple of 128 here)
        {
            const uint4* ph = reinterpret_cast<const uint4*>(
                Wh + (size_t)(n0 + sr) * K + k0 + ss * 8);
            const uint4* pl = reinterpret_cast<const uint4*>(
                Wl + (size_t)(n0 + sr) * K + k0 + ss * 8);
            uint4 h0 = ph[0], h1 = ph[1];
            uint4 l0 = pl[0], l1 = pl[1];
            *reinterpret_cast<uint4*>(&Bh[sr][((ss + 0) ^ sw) * 8]) = h0;
            *reinterpret_cast<uint4*>(&Bh[sr][((ss + 1) ^ sw) * 8]) = h1;
            *reinterpret_cast<uint4*>(&Bl[sr][((ss + 0) ^ sw) * 8]) = l0;
            *reinterpret_cast<uint4*>(&Bl[sr][((ss + 1) ^ sw) * 8]) = l1;
        }
        __syncthreads();
        // fragments: A row = lane&15, k = 8*(lane>>4)+i (one b128 each)
        short8 af[4], bhf[4], blf[4];
#pragma unroll
        for (int mi = 0; mi < 4; mi++) {
            int row = wr + mi * 16 + lm;
            af[mi] = *reinterpret_cast<const short8*>(
                &As[row][(g ^ ((row >> 1) & 3)) * 8]);
        }
#pragma unroll
        for (int ni = 0; ni < 4; ni++) {
            int row = wc + ni * 16 + lm;
            int off = (g ^ ((row >> 1) & 3)) * 8;
            bhf[ni] = *reinterpret_cast<const short8*>(&Bh[row][off]);
            blf[ni] = *reinterpret_cast<const short8*>(&Bl[row][off]);
        }
#pragma unroll
        for (int mi = 0; mi < 4; mi++)
#pragma unroll
            for (int ni = 0; ni < 4; ni++) {
                acc[mi][ni] = __builtin_amdgcn_mfma_f32_16x16x32_bf16(
                    af[mi], bhf[ni], acc[mi][ni], 0, 0, 0);
                acc[mi][ni] = __builtin_amdgcn_mfma_f32_16x16x32_bf16(
                    af[mi], blf[ni], acc[mi][ni], 0, 0, 0);
            }
        __syncthreads();
    }

    // epilogue: C/D layout col = lane&15, row = (lane>>4)*4 + j  [m89-verified]
#pragma unroll
    for (int mi = 0; mi < 4; mi++) {
#pragma unroll
        for (int j = 0; j < 4; j++) {
            int row = m0 + wr + mi * 16 + g * 4 + j;
            if (row >= M) continue;
#pragma unroll
            for (int ni = 0; ni < 4; ni++) {
                int col = n0 + wc + ni * 16 + lm;
                float v = acc[mi][ni][j];
                if (bias) v += bias[col];
                v = finclamp(v);
                if (CT == 0) {
                    ((float*)Cv)[(size_t)row * N + col] = v;
                } else {
                    ((ushort_t*)Cv)[(size_t)row * N + col] = f2b_raw(v);
                }
            }
        }
    }
}

// ---------- init kernels ----------
__global__ void fill_bias_k(float* __restrict__ o, const float* __restrict__ b1,
                            const float* __restrict__ b2, int n) {
    int i = blockIdx.x * 256 + threadIdx.x;
    if (i >= n) return;
    int f = i & 255;
    float v = b1[f];
    if (b2) v += b2[f];
    o[i] = v;
}

// ---------- CSR build: counting sort of edges by dst ----------
__global__ void zero2_k(int* __restrict__ a, int* __restrict__ b, int n) {
    int i = blockIdx.x * 256 + threadIdx.x;
    if (i < n) { a[i] = 0; b[i] = 0; }
}

__global__ void hist_k(const int* __restrict__ dst, int* __restrict__ cnt, int E) {
    int e = blockIdx.x * 256 + threadIdx.x;
    if (e < E) atomicAdd(&cnt[dst[e]], 1);
}

// single-workgroup exclusive scan of cnt[0..n) -> off[0..n], off[n] = total.
__global__ __launch_bounds__(1024) void scan_k(const int* __restrict__ cnt,
                                               int* __restrict__ off, int n) {
    __shared__ int wsum[16];
    __shared__ int cbase;
    int t = threadIdx.x, lane = t & 63, w = t >> 6;
    if (t == 0) cbase = 0;
    __syncthreads();
    for (int s0 = 0; s0 < n; s0 += 4096) {
        int i = s0 + t * 4;
        int v[4];
#pragma unroll
        for (int k = 0; k < 4; k++) v[k] = (i + k < n) ? cnt[i + k] : 0;
        int ts = v[0] + v[1] + v[2] + v[3];
        int x = ts;
#pragma unroll
        for (int sh = 1; sh < 64; sh <<= 1) {
            int y = __shfl_up(x, sh);
            if (lane >= sh) x += y;
        }
        if (lane == 63) wsum[w] = x;
        int base_read = cbase;
        __syncthreads();
        int wbase = 0;
        for (int k = 0; k < w; k++) wbase += wsum[k];
        int excl = base_read + wbase + (x - ts);
#pragma unroll
        for (int k = 0; k < 4; k++) {
            if (i + k < n) off[i + k] = excl;
            excl += v[k];
        }
        __syncthreads();
        if (t == 0) {
            int tot = 0;
            for (int k = 0; k < 16; k++) tot += wsum[k];
            cbase += tot;
        }
        __syncthreads();
    }
    if (threadIdx.x == 0) off[n] = cbase;
}

__global__ void permsrc_k(const int* __restrict__ dst, const int* __restrict__ src,
                          const int* __restrict__ off, int* __restrict__ cur,
                          int* __restrict__ ssrc, int E) {
    int e = blockIdx.x * 256 + threadIdx.x;
    if (e >= E) return;
    int d = dst[e];
    int slot = atomicAdd(&cur[d], 1);
    ssrc[off[d] + slot] = src[e];
}

// ---------- fused GATv2 gather: one wave per dst node, online softmax ----------
__global__ __launch_bounds__(256) void gat_gather_k(
    const ushort_t* __restrict__ xl, const ushort_t* __restrict__ xr,
    const float* __restrict__ att, const int* __restrict__ off,
    const int* __restrict__ ssrc, float* __restrict__ out, int Nd)
{
    int d = blockIdx.x * 4 + (threadIdx.x >> 6);
    if (d >= Nd) return;
    int j0 = off[d], j1 = off[d + 1];
    if (j0 == j1) return;           // zero in-degree: out keeps its bias fill
    int lane = threadIdx.x & 63;
    int f = lane * 4;
    float4 qa = *reinterpret_cast<const float4*>(att + f);
    uint2 qr = *reinterpret_cast<const uint2*>(xr + (size_t)d * FDIM + f);
    float r0 = blo(qr.x), r1 = bhi(qr.x), r2 = blo(qr.y), r3 = bhi(qr.y);

    float m = -1e30f, den = 0.f;
    float a0 = 0.f, a1 = 0.f, a2 = 0.f, a3 = 0.f;
    for (int j = j0; j < j1; ++j) {
        int s = ssrc[j];
        uint2 ql = *reinterpret_cast<const uint2*>(xl + (size_t)s * FDIM + f);
        float l0 = blo(ql.x), l1 = bhi(ql.x), l2 = blo(ql.y), l3 = bhi(ql.y);
        float v0 = l0 + r0, v1 = l1 + r1, v2 = l2 + r2, v3 = l3 + r3;
        v0 = (v0 > 0.f) ? v0 : 0.2f * v0;
        v1 = (v1 > 0.f) ? v1 : 0.2f * v1;
        v2 = (v2 > 0.f) ? v2 : 0.2f * v2;
        v3 = (v3 > 0.f) ? v3 : 0.2f * v3;
        float lg = qa.x * v0 + qa.y * v1 + qa.z * v2 + qa.w * v3;
        lg += __shfl_xor(lg, 1);
        lg += __shfl_xor(lg, 2);
        lg += __shfl_xor(lg, 4);
        lg += __shfl_xor(lg, 8);
        float mn = fmaxf(m, lg);
        float sc = expf(m - mn);
        float z  = expf(lg - mn);
        den = den * sc + z;
        a0 = a0 * sc + z * l0;
        a1 = a1 * sc + z * l1;
        a2 = a2 * sc + z * l2;
        a3 = a3 * sc + z * l3;
        m = mn;
    }
    float inv = (den > 0.f) ? 1.f / den : 0.f;
    float* op = out + (size_t)d * FDIM + f;
    float4 o = *reinterpret_cast<float4*>(op);
    o.x += finclamp(a0 * inv);
    o.y += finclamp(a1 * inv);
    o.z += finclamp(a2 * inv);
    o.w += finclamp(a3 * inv);
    *reinterpret_cast<float4*>(op) = o;
}

// ---------- combine: x = elu(scale * o) -> bf16 ----------
__global__ void combine_elu_k(const float* __restrict__ o, ushort_t* __restrict__ x,
                              float scale, int n)
{
    int i = blockIdx.x * 256 + threadIdx.x;
    if (i >= n) return;
    float v = scale * o[i];
    v = (v > 0.f) ? v : (expf(v) - 1.f);
    x[i] = f2b_raw(finclamp(v));
}

// ---------- host launch ----------
extern "C" void kernel_launch(void* const* d_in, const int* in_sizes, int n_in,
                              void* d_out, int out_size, void* d_ws, size_t ws_size,
                              hipStream_t stream) {
    (void)in_sizes; (void)n_in; (void)out_size;
    const float* x_table = (const float*)d_in[0];
    const float* x_column = (const float*)d_in[1];
    const float* x_fk = (const float*)d_in[2];
    const float* lin_w = (const float*)d_in[3];   // [3,256,64]
    const float* lin_b = (const float*)d_in[4];   // [3,64]
    const float* out_w = (const float*)d_in[5];   // [3,256,256]
    const float* out_b = (const float*)d_in[6];   // [3,256]
    const float* Wl0 = (const float*)d_in[7];     // [4,64,256]
    const float* Wr0 = (const float*)d_in[8];
    const float* att0 = (const float*)d_in[9];    // [4,4,64]
    const float* b0 = (const float*)d_in[10];     // [4,256]
    const float* Wl1 = (const float*)d_in[11];    // [4,256,256]
    const float* Wr1 = (const float*)d_in[12];
    const float* att1 = (const float*)d_in[13];
    const float* b1 = (const float*)d_in[14];
    const int* src_hc = (const int*)d_in[15];
    const int* dst_hc = (const int*)d_in[16];
    const int* src_bt = (const int*)d_in[17];
    const int* dst_bt = (const int*)d_in[18];
    const int* src_is = (const int*)d_in[19];
    const int* dst_is = (const int*)d_in[20];
    const int* src_pt = (const int*)d_in[21];
    const int* dst_pt = (const int*)d_in[22];
    float* out = (float*)d_out;

    // ---- carve workspace ----
    char* p = (char*)d_ws;
    auto alloc = [&](size_t bytes) -> char* {
        char* r = p;
        p += (bytes + 255) & ~(size_t)255;
        return r;
    };
    ushort_t* xt = (ushort_t*)alloc((size_t)NT * FDIM * 2);
    ushort_t* xc = (ushort_t*)alloc((size_t)NC * FDIM * 2);
    ushort_t* xf = (ushort_t*)alloc((size_t)NF * FDIM * 2);
    ushort_t* xl = (ushort_t*)alloc((size_t)NC * FDIM * 2);
    ushort_t* xr = (ushort_t*)alloc((size_t)NC * FDIM * 2);
    float* o_c = (float*)alloc((size_t)NC * FDIM * 4);
    float* o_t = (float*)alloc((size_t)NT * FDIM * 4);
    float* o_f = (float*)alloc((size_t)NF * FDIM * 4);
    int* off_hc = (int*)alloc((size_t)(NC + 1) * 4);
    int* off_bt = (int*)alloc((size_t)(NT + 1) * 4);
    int* off_is = (int*)alloc((size_t)(NF + 1) * 4);
    int* off_pt = (int*)alloc((size_t)(NC + 1) * 4);
    int* ssrc_hc = (int*)alloc((size_t)E_HC * 4);
    int* ssrc_bt = (int*)alloc((size_t)E_BT * 4);
    int* ssrc_is = (int*)alloc((size_t)E_IS * 4);
    int* ssrc_pt = (int*)alloc((size_t)E_PT * 4);
    int* cnt = (int*)alloc((size_t)NC * 4);
    int* cur = (int*)alloc((size_t)NC * 4);
    // transposed bf16 hi/lo weights: [type][N=256][K]
    ushort_t* wl_h0 = (ushort_t*)alloc((size_t)4 * 64 * 256 * 2);
    ushort_t* wl_l0 = (ushort_t*)alloc((size_t)4 * 64 * 256 * 2);
    ushort_t* wr_h0 = (ushort_t*)alloc((size_t)4 * 64 * 256 * 2);
    ushort_t* wr_l0 = (ushort_t*)alloc((size_t)4 * 64 * 256 * 2);
    ushort_t* wl_h1 = (ushort_t*)alloc((size_t)4 * 256 * 256 * 2);
    ushort_t* wl_l1 = (ushort_t*)alloc((size_t)4 * 256 * 256 * 2);
    ushort_t* wr_h1 = (ushort_t*)alloc((size_t)4 * 256 * 256 * 2);
    ushort_t* wr_l1 = (ushort_t*)alloc((size_t)4 * 256 * 256 * 2);
    ushort_t* ow_h = (ushort_t*)alloc((size_t)3 * 256 * 256 * 2);
    ushort_t* ow_l = (ushort_t*)alloc((size_t)3 * 256 * 256 * 2);
    if ((size_t)(p - (char*)d_ws) > ws_size) return;

    // ---- weight split/transpose (once) ----
    auto wsplit = [&](const float* W, ushort_t* Wh, ushort_t* Wlo, int K) {
        int total = K * 256;
        hipLaunchKernelGGL(wsplit_k, dim3((total + 255) / 256), dim3(256), 0, stream,
                           W, Wh, Wlo, K);
    };
    for (int ty = 0; ty < 4; ty++) {
        wsplit(Wl0 + (size_t)ty * 64 * 256, wl_h0 + (size_t)ty * 64 * 256,
               wl_l0 + (size_t)ty * 64 * 256, 64);
        wsplit(Wr0 + (size_t)ty * 64 * 256, wr_h0 + (size_t)ty * 64 * 256,
               wr_l0 + (size_t)ty * 64 * 256, 64);
        wsplit(Wl1 + (size_t)ty * 256 * 256, wl_h1 + (size_t)ty * 256 * 256,
               wl_l1 + (size_t)ty * 256 * 256, 256);
        wsplit(Wr1 + (size_t)ty * 256 * 256, wr_h1 + (size_t)ty * 256 * 256,
               wr_l1 + (size_t)ty * 256 * 256, 256);
    }
    for (int i = 0; i < 3; i++)
        wsplit(out_w + (size_t)i * 256 * 256, ow_h + (size_t)i * 256 * 256,
               ow_l + (size_t)i * 256 * 256, 256);

    // ---- CSR build (once; reused by both layers) ----
    auto build_csr = [&](const int* dst, const int* src, int E, int Nd,
                         int* off, int* ssrc) {
        hipLaunchKernelGGL(zero2_k, dim3((Nd + 255) / 256), dim3(256), 0, stream,
                           cnt, cur, Nd);
        hipLaunchKernelGGL(hist_k, dim3((E + 255) / 256), dim3(256), 0, stream,
                           dst, cnt, E);
        hipLaunchKernelGGL(scan_k, dim3(1), dim3(1024), 0, stream, cnt, off, Nd);
        hipLaunchKernelGGL(permsrc_k, dim3((E + 255) / 256), dim3(256), 0, stream,
                           dst, src, off, cur, ssrc, E);
    };
    build_csr(dst_hc, src_hc, E_HC, NC, off_hc, ssrc_hc);
    build_csr(dst_bt, src_bt, E_BT, NT, off_bt, ssrc_bt);
    build_csr(dst_is, src_is, E_IS, NF, off_is, ssrc_is);
    build_csr(dst_pt, src_pt, E_PT, NC, off_pt, ssrc_pt);

    // ---- input projections (fp32 A, N=64): VALU GEMM ----
    auto gemm_fb = [&](const float* A, const float* W, const float* bias,
                       ushort_t* C, int M, int N, int K, int act) {
        hipLaunchKernelGGL(gemm_k, dim3((M + BM - 1) / BM, N / BN), dim3(256), 0,
                           stream, A, W, bias, C, M, N, K, act);
    };
    gemm_fb(x_table, lin_w + 0 * 256 * 64, lin_b + 0 * 64, xt, NT, 64, 256, 1);
    gemm_fb(x_column, lin_w + 1 * 256 * 64, lin_b + 1 * 64, xc, NC, 64, 256, 1);
    gemm_fb(x_fk, lin_w + 2 * 256 * 64, lin_b + 2 * 64, xf, NF, 64, 256, 1);

    // ---- MFMA GEMMs (bf16 A, N=256) ----
    auto gemm_mb = [&](const ushort_t* A, const ushort_t* Wh, const ushort_t* Wlo,
                       ushort_t* C, int M, int K) {
        hipLaunchKernelGGL((gemm_mfma_k<1>), dim3((M + 127) / 128, 2), dim3(256), 0,
                           stream, A, Wh, Wlo, (const float*)nullptr, (void*)C,
                           M, 256, K);
    };
    auto gemm_mf = [&](const ushort_t* A, const ushort_t* Wh, const ushort_t* Wlo,
                       const float* bias, float* C, int M, int K) {
        hipLaunchKernelGGL((gemm_mfma_k<0>), dim3((M + 127) / 128, 2), dim3(256), 0,
                           stream, A, Wh, Wlo, bias, (void*)C, M, 256, K);
    };

    auto run_edge_type = [&](const ushort_t* xsrc, int Ns, const ushort_t* xdst, int Nd,
                             const int* off, const int* ssrc,
                             const ushort_t* wlh, const ushort_t* wll,
                             const ushort_t* wrh, const ushort_t* wrl,
                             const float* att_t, float* obuf, int Kd) {
        gemm_mb(xsrc, wlh, wll, xl, Ns, Kd);
        gemm_mb(xdst, wrh, wrl, xr, Nd, Kd);
        hipLaunchKernelGGL(gat_gather_k, dim3((Nd + 3) / 4), dim3(256), 0, stream,
                           xl, xr, att_t, off, ssrc, obuf, Nd);
    };

    for (int l = 0; l < 2; l++) {
        const ushort_t* wlh = l ? wl_h1 : wl_h0;
        const ushort_t* wll = l ? wl_l1 : wl_l0;
        const ushort_t* wrh = l ? wr_h1 : wr_h0;
        const ushort_t* wrl = l ? wr_l1 : wr_l0;
        const float* att = l ? att1 : att0;
        const float* bb = l ? b1 : b0;
        int Kd = l ? 256 : 64;
        size_t ws_t = (size_t)Kd * 256;   // per-type stride in transposed weights

        hipLaunchKernelGGL(fill_bias_k, dim3((NT * FDIM + 255) / 256), dim3(256), 0, stream,
                           o_t, bb + 1 * FDIM, (const float*)nullptr, NT * FDIM);
        hipLaunchKernelGGL(fill_bias_k, dim3((NF * FDIM + 255) / 256), dim3(256), 0, stream,
                           o_f, bb + 2 * FDIM, (const float*)nullptr, NF * FDIM);
        hipLaunchKernelGGL(fill_bias_k, dim3((NC * FDIM + 255) / 256), dim3(256), 0, stream,
                           o_c, bb + 0 * FDIM, bb + 3 * FDIM, NC * FDIM);

        run_edge_type(xt, NT, xc, NC, off_hc, ssrc_hc,
                      wlh + 0 * ws_t, wll + 0 * ws_t, wrh + 0 * ws_t, wrl + 0 * ws_t,
                      att + 0 * FDIM, o_c, Kd);
        run_edge_type(xc, NC, xt, NT, off_bt, ssrc_bt,
                      wlh + 1 * ws_t, wll + 1 * ws_t, wrh + 1 * ws_t, wrl + 1 * ws_t,
                      att + 1 * FDIM, o_t, Kd);
        run_edge_type(xc, NC, xf, NF, off_is, ssrc_is,
                      wlh + 2 * ws_t, wll + 2 * ws_t, wrh + 2 * ws_t, wrl + 2 * ws_t,
                      att + 2 * FDIM, o_f, Kd);
        run_edge_type(xf, NF, xc, NC, off_pt, ssrc_pt,
                      wlh + 3 * ws_t, wll + 3 * ws_t, wrh + 3 * ws_t, wrl + 3 * ws_t,
                      att + 3 * FDIM, o_c, Kd);

        hipLaunchKernelGGL(combine_elu_k, dim3((NT * FDIM + 255) / 256), dim3(256), 0, stream,
                           o_t, xt, 1.0f, NT * FDIM);
        hipLaunchKernelGGL(combine_elu_k, dim3((NC * FDIM + 255) / 256), dim3(256), 0, stream,
                           o_c, xc, 0.5f, NC * FDIM);
        hipLaunchKernelGGL(combine_elu_k, dim3((NF * FDIM + 255) / 256), dim3(256), 0, stream,
                           o_f, xf, 1.0f, NF * FDIM);
    }

    // ---- output projections -> d_out (concat xt, xc, xf), fp32 ----
    gemm_mf(xt, ow_h + 0 * 256 * 256, ow_l + 0 * 256 * 256, out_b + 0 * 256,
            out, NT, 256);
    gemm_mf(xc, ow_h + 1 * 256 * 256, ow_l + 1 * 256 * 256, out_b + 1 * 256,
            out + (size_t)NT * FDIM, NC, 256);
    gemm_mf(xf, ow_h + 2 * 256 * 256, ow_l + 2 * 256 * 256, out_b + 2 * 256,
            out + (size_t)(NT + NC) * FDIM, NF, 256);
}

// Round 3
// 1935.156 us; speedup vs baseline: 4.0861x; 1.3729x over previous
//
#include <hip/hip_runtime.h>
#include <stdint.h>

typedef unsigned short ushort_t;
typedef unsigned int uint32;

// ---------- sizes (fixed by the problem) ----------
#define NT 20000
#define NC 200000
#define NF 40000
#define E_HC 200000
#define E_BT 200000
#define E_IS 80000
#define E_PT 80000
#define FDIM 256   // H*D
#define NHEAD 4
#define DHEAD 64

typedef __attribute__((ext_vector_type(8))) short short8;
typedef __attribute__((ext_vector_type(4))) float f32x4;

// ---------- helpers ----------
__device__ __forceinline__ float blo(uint32 u) { return __uint_as_float(u << 16); }
__device__ __forceinline__ float bhi(uint32 u) { return __uint_as_float(u & 0xFFFF0000u); }
__device__ __forceinline__ ushort_t f2b_raw(float f) {
    unsigned u = __float_as_uint(f);
    unsigned r = u + 0x7fffu + ((u >> 16) & 1u);   // RNE
    return (ushort_t)(r >> 16);
}
__device__ __forceinline__ float finclamp(float v) {
    // NaN -> -1e30 (finite); +-inf -> +-1e30. No-op for sane values.
    return fminf(fmaxf(v, -1e30f), 1e30f);
}

// ---------- VALU GEMM (kept for fp32-input projections, N=64) ----------
// C[M,N] = act(A[M,K] @ W[K,N] + bias[N]); A fp32, C bf16. BM=128,BN=64,BK=16.
#define BM 128
#define BN 64
#define BK 16
__global__ __launch_bounds__(256) void gemm_k(
    const float* __restrict__ A, const float* __restrict__ W,
    const float* __restrict__ bias, ushort_t* __restrict__ C,
    int M, int N, int K, int act)
{
    __shared__ float As[BK][BM + 1];
    __shared__ float Ws[BK][BN + 1];
    const int t  = threadIdx.x;
    const int m0 = blockIdx.x * BM;
    const int n0 = blockIdx.y * BN;
    const int tx = t & 15, ty = t >> 4;
    const int am = t >> 1;           // 0..127
    const int ak = (t & 1) * 8;      // 0 or 8
    const int wk = t >> 4;           // 0..15
    const int wn = (t & 15) * 4;     // 0..60

    float acc[8][4];
#pragma unroll
    for (int i = 0; i < 8; i++)
#pragma unroll
        for (int j = 0; j < 4; j++) acc[i][j] = 0.f;

    for (int k0 = 0; k0 < K; k0 += BK) {
        {
            float vals[8];
            int arow = m0 + am;
            if (arow < M) {
                const float4* p = reinterpret_cast<const float4*>(
                    A + (size_t)arow * K + k0 + ak);
                float4 q0 = p[0], q1 = p[1];
                vals[0] = q0.x; vals[1] = q0.y; vals[2] = q0.z; vals[3] = q0.w;
                vals[4] = q1.x; vals[5] = q1.y; vals[6] = q1.z; vals[7] = q1.w;
            } else {
#pragma unroll
                for (int i = 0; i < 8; i++) vals[i] = 0.f;
            }
#pragma unroll
            for (int i = 0; i < 8; i++) As[ak + i][am] = vals[i];
        }
        {
            float4 q = *reinterpret_cast<const float4*>(
                W + (size_t)(k0 + wk) * N + n0 + wn);
            Ws[wk][wn + 0] = q.x;
            Ws[wk][wn + 1] = q.y;
            Ws[wk][wn + 2] = q.z;
            Ws[wk][wn + 3] = q.w;
        }
        __syncthreads();
#pragma unroll
        for (int kk = 0; kk < BK; ++kk) {
            float a[8], w[4];
#pragma unroll
            for (int i = 0; i < 8; i++) a[i] = As[kk][ty * 8 + i];
#pragma unroll
            for (int j = 0; j < 4; j++) w[j] = Ws[kk][tx * 4 + j];
#pragma unroll
            for (int i = 0; i < 8; i++)
#pragma unroll
                for (int j = 0; j < 4; j++) acc[i][j] += a[i] * w[j];
        }
        __syncthreads();
    }

    float bv[4] = {0.f, 0.f, 0.f, 0.f};
    if (bias) {
#pragma unroll
        for (int j = 0; j < 4; j++) bv[j] = bias[n0 + tx * 4 + j];
    }
#pragma unroll
    for (int i = 0; i < 8; i++) {
        int r = m0 + ty * 8 + i;
        if (r >= M) continue;
        size_t base = (size_t)r * N + n0 + tx * 4;
        float v[4];
#pragma unroll
        for (int j = 0; j < 4; j++) {
            float x = acc[i][j] + bv[j];
            if (act == 1) x = (x > 0.f) ? x : 0.01f * x;
            v[j] = finclamp(x);
        }
        uint32 lo = ((uint32)f2b_raw(v[1]) << 16) | (uint32)f2b_raw(v[0]);
        uint32 hi = ((uint32)f2b_raw(v[3]) << 16) | (uint32)f2b_raw(v[2]);
        *reinterpret_cast<uint2*>(C + base) = make_uint2(lo, hi);
    }
}

// ---------- weight split: W[K][256] fp32 -> Wt_hi/Wt_lo [256][K] bf16 ----------
// hi = bf16(w); lo = bf16(w - hi). A@(hi+lo) ~= fp32-exact weights (2^-17 rel).
__global__ void wsplit_k(const float* __restrict__ W, ushort_t* __restrict__ Wh,
                         ushort_t* __restrict__ Wl, int K) {
    int i = blockIdx.x * 256 + threadIdx.x;
    if (i >= K * 256) return;
    int k = i >> 8, n = i & 255;
    float w = W[i];
    ushort_t h = f2b_raw(w);
    float hf = __uint_as_float((uint32)h << 16);
    ushort_t l = f2b_raw(w - hf);
    Wh[(size_t)n * K + k] = h;
    Wl[(size_t)n * K + k] = l;
}

// ---------- MFMA GEMM: C[M,256] = A[M,K](bf16) @ W(hi+lo) + bias ----------
// 128x128 tile, BK=32; 4 waves 2x2, each 64x64 via 4x4 16x16x32 frags.
// Two MFMAs (hi,lo) per fragment into one fp32 acc. CT: 0=f32 out, 1=bf16 out.
// LDS [128][32] bf16, 16B-slot XOR swizzle: slot ^= (row>>1)&3.
template<int CT>
__global__ __launch_bounds__(256) void gemm_mfma_k(
    const ushort_t* __restrict__ A, const ushort_t* __restrict__ Wh,
    const ushort_t* __restrict__ Wl, const float* __restrict__ bias,
    void* __restrict__ Cv, int M, int N, int K)
{
    __shared__ __align__(16) ushort_t As[128][32];
    __shared__ __align__(16) ushort_t Bh[128][32];
    __shared__ __align__(16) ushort_t Bl[128][32];
    const int t = threadIdx.x;
    const int lane = t & 63;
    const int w = t >> 6;
    const int wr = (w >> 1) * 64, wc = (w & 1) * 64;
    const int m0 = blockIdx.x * 128;
    const int n0 = blockIdx.y * 128;
    const int lm = lane & 15, g = lane >> 4;

    f32x4 acc[4][4];
#pragma unroll
    for (int mi = 0; mi < 4; mi++)
#pragma unroll
        for (int ni = 0; ni < 4; ni++) acc[mi][ni] = (f32x4){0.f, 0.f, 0.f, 0.f};

    const int sr = t >> 1;          // staging row 0..127
    const int ss = (t & 1) * 2;     // slots {0,1} or {2,3}
    const int sw = (sr >> 1) & 3;   // swizzle for this staging row

    for (int k0 = 0; k0 < K; k0 += 32) {
        {
            int row = m0 + sr;
            uint4 q0 = make_uint4(0u, 0u, 0u, 0u), q1 = q0;
            if (row < M) {
                const uint4* p = reinterpret_cast<const uint4*>(
                    A + (size_t)row * K + k0 + ss * 8);
                q0 = p[0]; q1 = p[1];
            }
            *reinterpret_cast<uint4*>(&As[sr][((ss + 0) ^ sw) * 8]) = q0;
            *reinterpret_cast<uint4*>(&As[sr][((ss + 1) ^ sw) * 8]) = q1;
        }
        {
            const uint4* ph = reinterpret_cast<const uint4*>(
                Wh + (size_t)(n0 + sr) * K + k0 + ss * 8);
            const uint4* pl = reinterpret_cast<const uint4*>(
                Wl + (size_t)(n0 + sr) * K + k0 + ss * 8);
            uint4 h0 = ph[0], h1 = ph[1];
            uint4 l0 = pl[0], l1 = pl[1];
            *reinterpret_cast<uint4*>(&Bh[sr][((ss + 0) ^ sw) * 8]) = h0;
            *reinterpret_cast<uint4*>(&Bh[sr][((ss + 1) ^ sw) * 8]) = h1;
            *reinterpret_cast<uint4*>(&Bl[sr][((ss + 0) ^ sw) * 8]) = l0;
            *reinterpret_cast<uint4*>(&Bl[sr][((ss + 1) ^ sw) * 8]) = l1;
        }
        __syncthreads();
        short8 af[4], bhf[4], blf[4];
#pragma unroll
        for (int mi = 0; mi < 4; mi++) {
            int row = wr + mi * 16 + lm;
            af[mi] = *reinterpret_cast<const short8*>(
                &As[row][(g ^ ((row >> 1) & 3)) * 8]);
        }
#pragma unroll
        for (int ni = 0; ni < 4; ni++) {
            int row = wc + ni * 16 + lm;
            int off = (g ^ ((row >> 1) & 3)) * 8;
            bhf[ni] = *reinterpret_cast<const short8*>(&Bh[row][off]);
            blf[ni] = *reinterpret_cast<const short8*>(&Bl[row][off]);
        }
#pragma unroll
        for (int mi = 0; mi < 4; mi++)
#pragma unroll
            for (int ni = 0; ni < 4; ni++) {
                acc[mi][ni] = __builtin_amdgcn_mfma_f32_16x16x32_bf16(
                    af[mi], bhf[ni], acc[mi][ni], 0, 0, 0);
                acc[mi][ni] = __builtin_amdgcn_mfma_f32_16x16x32_bf16(
                    af[mi], blf[ni], acc[mi][ni], 0, 0, 0);
            }
        __syncthreads();
    }

    // epilogue: C/D layout col = lane&15, row = (lane>>4)*4 + j  [m89-verified]
#pragma unroll
    for (int mi = 0; mi < 4; mi++) {
#pragma unroll
        for (int j = 0; j < 4; j++) {
            int row = m0 + wr + mi * 16 + g * 4 + j;
            if (row >= M) continue;
#pragma unroll
            for (int ni = 0; ni < 4; ni++) {
                int col = n0 + wc + ni * 16 + lm;
                float v = acc[mi][ni][j];
                if (bias) v += bias[col];
                v = finclamp(v);
                if (CT == 0) {
                    ((float*)Cv)[(size_t)row * N + col] = v;
                } else {
                    ((ushort_t*)Cv)[(size_t)row * N + col] = f2b_raw(v);
                }
            }
        }
    }
}

// ---------- CSR build: counting sort of edges by dst ----------
__global__ void zero2_k(int* __restrict__ a, int* __restrict__ b, int n) {
    int i = blockIdx.x * 256 + threadIdx.x;
    if (i < n) { a[i] = 0; b[i] = 0; }
}

__global__ void hist_k(const int* __restrict__ dst, int* __restrict__ cnt, int E) {
    int e = blockIdx.x * 256 + threadIdx.x;
    if (e < E) atomicAdd(&cnt[dst[e]], 1);
}

// parallel 3-phase exclusive scan: per-block scan -> 1-wave top scan -> fixup
__global__ __launch_bounds__(1024) void scan_blk_k(const int* __restrict__ cnt,
                                                   int* __restrict__ off,
                                                   int* __restrict__ bsum, int n) {
    __shared__ int wsum[16];
    int t = threadIdx.x, lane = t & 63, w = t >> 6;
    int i = blockIdx.x * 4096 + t * 4;
    int v[4];
#pragma unroll
    for (int k = 0; k < 4; k++) v[k] = (i + k < n) ? cnt[i + k] : 0;
    int ts = v[0] + v[1] + v[2] + v[3];
    int x = ts;
#pragma unroll
    for (int sh = 1; sh < 64; sh <<= 1) {
        int y = __shfl_up(x, sh);
        if (lane >= sh) x += y;
    }
    if (lane == 63) wsum[w] = x;
    __syncthreads();
    int wbase = 0;
    for (int k = 0; k < w; k++) wbase += wsum[k];
    int excl = wbase + (x - ts);
#pragma unroll
    for (int k = 0; k < 4; k++) {
        if (i + k < n) off[i + k] = excl;
        excl += v[k];
    }
    if (t == 1023) bsum[blockIdx.x] = wbase + x;   // block total
}

// single wave: exclusive scan of nb (<=64) block sums; also writes off[n]=total
__global__ void scan_top_k(int* __restrict__ bsum, int* __restrict__ off,
                           int n, int nb) {
    int lane = threadIdx.x;
    int v = (lane < nb) ? bsum[lane] : 0;
    int x = v;
#pragma unroll
    for (int sh = 1; sh < 64; sh <<= 1) {
        int y = __shfl_up(x, sh);
        if (lane >= sh) x += y;
    }
    if (lane < nb) bsum[lane] = x - v;
    if (lane == 63) off[n] = x;
}

__global__ void scan_fix_k(int* __restrict__ off, const int* __restrict__ bsum, int n) {
    int i = blockIdx.x * 256 + threadIdx.x;
    if (i < n) off[i] += bsum[i >> 12];
}

__global__ void permsrc_k(const int* __restrict__ dst, const int* __restrict__ src,
                          const int* __restrict__ off, int* __restrict__ cur,
                          int* __restrict__ ssrc, int E) {
    int e = blockIdx.x * 256 + threadIdx.x;
    if (e >= E) return;
    int d = dst[e];
    int slot = atomicAdd(&cur[d], 1);
    ssrc[off[d] + slot] = src[e];
}

// ---------- fused GATv2 gather + bias + ELU + bf16 store ----------
// One wave per dst node; lane owns features f..f+3. Online softmax per edge
// type (each type is an independent GAT). Second type optional (off2 != null).
__device__ __forceinline__ void gat_accum(
    const ushort_t* __restrict__ xl, const ushort_t* __restrict__ xr,
    const float* __restrict__ att, const int* __restrict__ off,
    const int* __restrict__ ssrc, int d, int f,
    float& o0, float& o1, float& o2, float& o3)
{
    int j0 = off[d], j1 = off[d + 1];
    if (j0 == j1) return;                       // empty segment: msg = 0
    float4 qa = *reinterpret_cast<const float4*>(att + f);
    uint2 qr = *reinterpret_cast<const uint2*>(xr + (size_t)d * FDIM + f);
    float r0 = blo(qr.x), r1 = bhi(qr.x), r2 = blo(qr.y), r3 = bhi(qr.y);
    float m = -1e30f, den = 0.f;
    float a0 = 0.f, a1 = 0.f, a2 = 0.f, a3 = 0.f;
    for (int j = j0; j < j1; ++j) {
        int s = ssrc[j];
        uint2 ql = *reinterpret_cast<const uint2*>(xl + (size_t)s * FDIM + f);
        float l0 = blo(ql.x), l1 = bhi(ql.x), l2 = blo(ql.y), l3 = bhi(ql.y);
        float v0 = l0 + r0, v1 = l1 + r1, v2 = l2 + r2, v3 = l3 + r3;
        v0 = (v0 > 0.f) ? v0 : 0.2f * v0;
        v1 = (v1 > 0.f) ? v1 : 0.2f * v1;
        v2 = (v2 > 0.f) ? v2 : 0.2f * v2;
        v3 = (v3 > 0.f) ? v3 : 0.2f * v3;
        float lg = qa.x * v0 + qa.y * v1 + qa.z * v2 + qa.w * v3;
        lg += __shfl_xor(lg, 1);
        lg += __shfl_xor(lg, 2);
        lg += __shfl_xor(lg, 4);
        lg += __shfl_xor(lg, 8);
        float mn = fmaxf(m, lg);
        float sc = expf(m - mn);
        float z  = expf(lg - mn);
        den = den * sc + z;
        a0 = a0 * sc + z * l0;
        a1 = a1 * sc + z * l1;
        a2 = a2 * sc + z * l2;
        a3 = a3 * sc + z * l3;
        m = mn;
    }
    float inv = (den > 0.f) ? 1.f / den : 0.f;
    o0 += finclamp(a0 * inv);
    o1 += finclamp(a1 * inv);
    o2 += finclamp(a2 * inv);
    o3 += finclamp(a3 * inv);
}

__global__ __launch_bounds__(256) void gat_gather2_k(
    const ushort_t* __restrict__ xl1, const ushort_t* __restrict__ xr1,
    const float* __restrict__ att1, const int* __restrict__ off1,
    const int* __restrict__ ssrc1,
    const ushort_t* __restrict__ xl2, const ushort_t* __restrict__ xr2,
    const float* __restrict__ att2, const int* __restrict__ off2,
    const int* __restrict__ ssrc2,
    const float* __restrict__ b1, const float* __restrict__ b2,
    float scale, ushort_t* __restrict__ xout, int Nd)
{
    int d = blockIdx.x * 4 + (threadIdx.x >> 6);
    if (d >= Nd) return;
    int lane = threadIdx.x & 63;
    int f = lane * 4;
    float o0 = 0.f, o1 = 0.f, o2 = 0.f, o3 = 0.f;
    gat_accum(xl1, xr1, att1, off1, ssrc1, d, f, o0, o1, o2, o3);
    if (off2) gat_accum(xl2, xr2, att2, off2, ssrc2, d, f, o0, o1, o2, o3);
    float4 bv = *reinterpret_cast<const float4*>(b1 + f);
    o0 += bv.x; o1 += bv.y; o2 += bv.z; o3 += bv.w;
    if (b2) {
        float4 b2v = *reinterpret_cast<const float4*>(b2 + f);
        o0 += b2v.x; o1 += b2v.y; o2 += b2v.z; o3 += b2v.w;
    }
    o0 *= scale; o1 *= scale; o2 *= scale; o3 *= scale;
    o0 = (o0 > 0.f) ? o0 : (expf(o0) - 1.f);
    o1 = (o1 > 0.f) ? o1 : (expf(o1) - 1.f);
    o2 = (o2 > 0.f) ? o2 : (expf(o2) - 1.f);
    o3 = (o3 > 0.f) ? o3 : (expf(o3) - 1.f);
    uint32 lo = ((uint32)f2b_raw(finclamp(o1)) << 16) | (uint32)f2b_raw(finclamp(o0));
    uint32 hi = ((uint32)f2b_raw(finclamp(o3)) << 16) | (uint32)f2b_raw(finclamp(o2));
    *reinterpret_cast<uint2*>(xout + (size_t)d * FDIM + f) = make_uint2(lo, hi);
}

// ---------- host launch ----------
extern "C" void kernel_launch(void* const* d_in, const int* in_sizes, int n_in,
                              void* d_out, int out_size, void* d_ws, size_t ws_size,
                              hipStream_t stream) {
    (void)in_sizes; (void)n_in; (void)out_size;
    const float* x_table = (const float*)d_in[0];
    const float* x_column = (const float*)d_in[1];
    const float* x_fk = (const float*)d_in[2];
    const float* lin_w = (const float*)d_in[3];   // [3,256,64]
    const float* lin_b = (const float*)d_in[4];   // [3,64]
    const float* out_w = (const float*)d_in[5];   // [3,256,256]
    const float* out_b = (const float*)d_in[6];   // [3,256]
    const float* Wl0 = (const float*)d_in[7];     // [4,64,256]
    const float* Wr0 = (const float*)d_in[8];
    const float* att0 = (const float*)d_in[9];    // [4,4,64]
    const float* b0 = (const float*)d_in[10];     // [4,256]
    const float* Wl1 = (const float*)d_in[11];    // [4,256,256]
    const float* Wr1 = (const float*)d_in[12];
    const float* att1 = (const float*)d_in[13];
    const float* b1 = (const float*)d_in[14];
    const int* src_hc = (const int*)d_in[15];
    const int* dst_hc = (const int*)d_in[16];
    const int* src_bt = (const int*)d_in[17];
    const int* dst_bt = (const int*)d_in[18];
    const int* src_is = (const int*)d_in[19];
    const int* dst_is = (const int*)d_in[20];
    const int* src_pt = (const int*)d_in[21];
    const int* dst_pt = (const int*)d_in[22];
    float* out = (float*)d_out;

    // ---- carve workspace (~613 MB) ----
    char* p = (char*)d_ws;
    auto alloc = [&](size_t bytes) -> char* {
        char* r = p;
        p += (bytes + 255) & ~(size_t)255;
        return r;
    };
    ushort_t* xt = (ushort_t*)alloc((size_t)NT * FDIM * 2);
    ushort_t* xc = (ushort_t*)alloc((size_t)NC * FDIM * 2);
    ushort_t* xf = (ushort_t*)alloc((size_t)NF * FDIM * 2);
    // per-edge-type projection buffers (all live simultaneously within a layer)
    ushort_t* pl_hc = (ushort_t*)alloc((size_t)NT * FDIM * 2);
    ushort_t* pr_hc = (ushort_t*)alloc((size_t)NC * FDIM * 2);
    ushort_t* pl_bt = (ushort_t*)alloc((size_t)NC * FDIM * 2);
    ushort_t* pr_bt = (ushort_t*)alloc((size_t)NT * FDIM * 2);
    ushort_t* pl_is = (ushort_t*)alloc((size_t)NC * FDIM * 2);
    ushort_t* pr_is = (ushort_t*)alloc((size_t)NF * FDIM * 2);
    ushort_t* pl_pt = (ushort_t*)alloc((size_t)NF * FDIM * 2);
    ushort_t* pr_pt = (ushort_t*)alloc((size_t)NC * FDIM * 2);
    int* off_hc = (int*)alloc((size_t)(NC + 1) * 4);
    int* off_bt = (int*)alloc((size_t)(NT + 1) * 4);
    int* off_is = (int*)alloc((size_t)(NF + 1) * 4);
    int* off_pt = (int*)alloc((size_t)(NC + 1) * 4);
    int* ssrc_hc = (int*)alloc((size_t)E_HC * 4);
    int* ssrc_bt = (int*)alloc((size_t)E_BT * 4);
    int* ssrc_is = (int*)alloc((size_t)E_IS * 4);
    int* ssrc_pt = (int*)alloc((size_t)E_PT * 4);
    int* cnt = (int*)alloc((size_t)NC * 4);
    int* cur = (int*)alloc((size_t)NC * 4);
    int* bsum = (int*)alloc((size_t)64 * 4);
    // transposed bf16 hi/lo weights: [type][N=256][K]
    ushort_t* wl_h0 = (ushort_t*)alloc((size_t)4 * 64 * 256 * 2);
    ushort_t* wl_l0 = (ushort_t*)alloc((size_t)4 * 64 * 256 * 2);
    ushort_t* wr_h0 = (ushort_t*)alloc((size_t)4 * 64 * 256 * 2);
    ushort_t* wr_l0 = (ushort_t*)alloc((size_t)4 * 64 * 256 * 2);
    ushort_t* wl_h1 = (ushort_t*)alloc((size_t)4 * 256 * 256 * 2);
    ushort_t* wl_l1 = (ushort_t*)alloc((size_t)4 * 256 * 256 * 2);
    ushort_t* wr_h1 = (ushort_t*)alloc((size_t)4 * 256 * 256 * 2);
    ushort_t* wr_l1 = (ushort_t*)alloc((size_t)4 * 256 * 256 * 2);
    ushort_t* ow_h = (ushort_t*)alloc((size_t)3 * 256 * 256 * 2);
    ushort_t* ow_l = (ushort_t*)alloc((size_t)3 * 256 * 256 * 2);
    if ((size_t)(p - (char*)d_ws) > ws_size) return;

    // ---- weight split/transpose (once) ----
    auto wsplit = [&](const float* W, ushort_t* Wh, ushort_t* Wlo, int K) {
        int total = K * 256;
        hipLaunchKernelGGL(wsplit_k, dim3((total + 255) / 256), dim3(256), 0, stream,
                           W, Wh, Wlo, K);
    };
    for (int ty = 0; ty < 4; ty++) {
        wsplit(Wl0 + (size_t)ty * 64 * 256, wl_h0 + (size_t)ty * 64 * 256,
               wl_l0 + (size_t)ty * 64 * 256, 64);
        wsplit(Wr0 + (size_t)ty * 64 * 256, wr_h0 + (size_t)ty * 64 * 256,
               wr_l0 + (size_t)ty * 64 * 256, 64);
        wsplit(Wl1 + (size_t)ty * 256 * 256, wl_h1 + (size_t)ty * 256 * 256,
               wl_l1 + (size_t)ty * 256 * 256, 256);
        wsplit(Wr1 + (size_t)ty * 256 * 256, wr_h1 + (size_t)ty * 256 * 256,
               wr_l1 + (size_t)ty * 256 * 256, 256);
    }
    for (int i = 0; i < 3; i++)
        wsplit(out_w + (size_t)i * 256 * 256, ow_h + (size_t)i * 256 * 256,
               ow_l + (size_t)i * 256 * 256, 256);

    // ---- CSR build (once; reused by both layers) ----
    auto build_csr = [&](const int* dst, const int* src, int E, int Nd,
                         int* off, int* ssrc) {
        int nb = (Nd + 4095) / 4096;
        hipLaunchKernelGGL(zero2_k, dim3((Nd + 255) / 256), dim3(256), 0, stream,
                           cnt, cur, Nd);
        hipLaunchKernelGGL(hist_k, dim3((E + 255) / 256), dim3(256), 0, stream,
                           dst, cnt, E);
        hipLaunchKernelGGL(scan_blk_k, dim3(nb), dim3(1024), 0, stream,
                           cnt, off, bsum, Nd);
        hipLaunchKernelGGL(scan_top_k, dim3(1), dim3(64), 0, stream,
                           bsum, off, Nd, nb);
        hipLaunchKernelGGL(scan_fix_k, dim3((Nd + 255) / 256), dim3(256), 0, stream,
                           off, bsum, Nd);
        hipLaunchKernelGGL(permsrc_k, dim3((E + 255) / 256), dim3(256), 0, stream,
                           dst, src, off, cur, ssrc, E);
    };
    build_csr(dst_hc, src_hc, E_HC, NC, off_hc, ssrc_hc);
    build_csr(dst_bt, src_bt, E_BT, NT, off_bt, ssrc_bt);
    build_csr(dst_is, src_is, E_IS, NF, off_is, ssrc_is);
    build_csr(dst_pt, src_pt, E_PT, NC, off_pt, ssrc_pt);

    // ---- input projections (fp32 A, N=64): VALU GEMM ----
    auto gemm_fb = [&](const float* A, const float* W, const float* bias,
                       ushort_t* C, int M, int N, int K, int act) {
        hipLaunchKernelGGL(gemm_k, dim3((M + BM - 1) / BM, N / BN), dim3(256), 0,
                           stream, A, W, bias, C, M, N, K, act);
    };
    gemm_fb(x_table, lin_w + 0 * 256 * 64, lin_b + 0 * 64, xt, NT, 64, 256, 1);
    gemm_fb(x_column, lin_w + 1 * 256 * 64, lin_b + 1 * 64, xc, NC, 64, 256, 1);
    gemm_fb(x_fk, lin_w + 2 * 256 * 64, lin_b + 2 * 64, xf, NF, 64, 256, 1);

    // ---- MFMA GEMM (bf16 A, N=256, bf16 C) ----
    auto gemm_mb = [&](const ushort_t* A, const ushort_t* Wh, const ushort_t* Wlo,
                       ushort_t* C, int M, int K) {
        hipLaunchKernelGGL((gemm_mfma_k<1>), dim3((M + 127) / 128, 2), dim3(256), 0,
                           stream, A, Wh, Wlo, (const float*)nullptr, (void*)C,
                           M, 256, K);
    };
    auto gemm_mf = [&](const ushort_t* A, const ushort_t* Wh, const ushort_t* Wlo,
                       const float* bias, float* C, int M, int K) {
        hipLaunchKernelGGL((gemm_mfma_k<0>), dim3((M + 127) / 128, 2), dim3(256), 0,
                           stream, A, Wh, Wlo, bias, (void*)C, M, 256, K);
    };

    for (int l = 0; l < 2; l++) {
        const ushort_t* wlh = l ? wl_h1 : wl_h0;
        const ushort_t* wll = l ? wl_l1 : wl_l0;
        const ushort_t* wrh = l ? wr_h1 : wr_h0;
        const ushort_t* wrl = l ? wr_l1 : wr_l0;
        const float* att = l ? att1 : att0;
        const float* bb = l ? b1 : b0;
        int Kd = l ? 256 : 64;
        size_t ws_t = (size_t)Kd * 256;   // per-type stride in transposed weights

        // all 8 projections first (xt/xc/xf fully consumed before overwrite)
        gemm_mb(xt, wlh + 0 * ws_t, wll + 0 * ws_t, pl_hc, NT, Kd);   // hc: src=t
        gemm_mb(xt, wrh + 1 * ws_t, wrl + 1 * ws_t, pr_bt, NT, Kd);   // bt: dst=t
        gemm_mb(xc, wrh + 0 * ws_t, wrl + 0 * ws_t, pr_hc, NC, Kd);   // hc: dst=c
        gemm_mb(xc, wlh + 1 * ws_t, wll + 1 * ws_t, pl_bt, NC, Kd);   // bt: src=c
        gemm_mb(xc, wlh + 2 * ws_t, wll + 2 * ws_t, pl_is, NC, Kd);   // is: src=c
        gemm_mb(xc, wrh + 3 * ws_t, wrl + 3 * ws_t, pr_pt, NC, Kd);   // pt: dst=c
        gemm_mb(xf, wrh + 2 * ws_t, wrl + 2 * ws_t, pr_is, NF, Kd);   // is: dst=f
        gemm_mb(xf, wlh + 3 * ws_t, wll + 3 * ws_t, pl_pt, NF, Kd);   // pt: src=f

        // fused gathers: bias + softmax-msg(s) + ELU -> bf16 next-layer feats
        hipLaunchKernelGGL(gat_gather2_k, dim3((NT + 3) / 4), dim3(256), 0, stream,
                           pl_bt, pr_bt, att + 1 * FDIM, off_bt, ssrc_bt,
                           (const ushort_t*)nullptr, (const ushort_t*)nullptr,
                           (const float*)nullptr, (const int*)nullptr,
                           (const int*)nullptr,
                           bb + 1 * FDIM, (const float*)nullptr, 1.0f, xt, NT);
        hipLaunchKernelGGL(gat_gather2_k, dim3((NF + 3) / 4), dim3(256), 0, stream,
                           pl_is, pr_is, att + 2 * FDIM, off_is, ssrc_is,
                           (const ushort_t*)nullptr, (const ushort_t*)nullptr,
                           (const float*)nullptr, (const int*)nullptr,
                           (const int*)nullptr,
                           bb + 2 * FDIM, (const float*)nullptr, 1.0f, xf, NF);
        hipLaunchKernelGGL(gat_gather2_k, dim3((NC + 3) / 4), dim3(256), 0, stream,
                           pl_hc, pr_hc, att + 0 * FDIM, off_hc, ssrc_hc,
                           pl_pt, pr_pt, att + 3 * FDIM, off_pt, ssrc_pt,
                           bb + 0 * FDIM, bb + 3 * FDIM, 0.5f, xc, NC);
    }

    // ---- output projections -> d_out (concat xt, xc, xf), fp32 ----
    gemm_mf(xt, ow_h + 0 * 256 * 256, ow_l + 0 * 256 * 256, out_b + 0 * 256,
            out, NT, 256);
    gemm_mf(xc, ow_h + 1 * 256 * 256, ow_l + 1 * 256 * 256, out_b + 1 * 256,
            out + (size_t)NT * FDIM, NC, 256);
    gemm_mf(xf, ow_h + 2 * 256 * 256, ow_l + 2 * 256 * 256, out_b + 2 * 256,
            out + (size_t)(NT + NC) * FDIM, NF, 256);
}

// Round 4
// 1649.040 us; speedup vs baseline: 4.7951x; 1.1735x over previous
//
#include <hip/hip_runtime.h>
#include <stdint.h>

typedef unsigned short ushort_t;
typedef unsigned int uint32;

// ---------- sizes (fixed by the problem) ----------
#define NT 20000
#define NC 200000
#define NF 40000
#define E_HC 200000
#define E_BT 200000
#define E_IS 80000
#define E_PT 80000
#define FDIM 256   // H*D
#define NHEAD 4
#define DHEAD 64

typedef _Float16 __attribute__((ext_vector_type(8))) half8;
typedef __attribute__((ext_vector_type(4))) float f32x4;

// ---------- helpers ----------
__device__ __forceinline__ ushort_t f2h(float f) {
    _Float16 h = (_Float16)f;       // v_cvt_f16_f32, RNE
    ushort_t v;
    __builtin_memcpy(&v, &h, 2);
    return v;
}
__device__ __forceinline__ float h2f_u(ushort_t v) {
    _Float16 h;
    __builtin_memcpy(&h, &v, 2);
    return (float)h;
}
__device__ __forceinline__ float hlo(uint32 u) { return h2f_u((ushort_t)(u & 0xffffu)); }
__device__ __forceinline__ float hhi(uint32 u) { return h2f_u((ushort_t)(u >> 16)); }
__device__ __forceinline__ float finclamp(float v) {
    // NaN -> -1e30 (finite); +-inf -> +-1e30. No-op for sane values.
    return fminf(fmaxf(v, -1e30f), 1e30f);
}

union U16x8 { ushort_t u[8]; uint4 q; };

// ---------- weight pack kernels (fp32 -> fp16, transposed to [N][K]) ----------
// layer weights: Wl/Wr are [4][K][256]; cat layouts:
//  ct [512][K]:  0-255 <- Wl[0] (hc src), 256-511 <- Wr[1] (bt dst)
//  cc [1024][K]: 0-255 <- Wr[0] (hc dst), 256-511 <- Wl[1] (bt src),
//                512-767 <- Wl[2] (is src), 768-1023 <- Wr[3] (pt dst)
//  cf [512][K]:  0-255 <- Wr[2] (is dst), 256-511 <- Wl[3] (pt src)
__global__ void pack_layer_k(const float* __restrict__ Wl, const float* __restrict__ Wr,
                             ushort_t* __restrict__ ct, ushort_t* __restrict__ cc,
                             ushort_t* __restrict__ cf, int K) {
    int i = blockIdx.x * 256 + threadIdx.x;
    int per = K * 256;
    if (i >= 8 * per) return;
    int s = i / per, r = i - s * per;
    int k = r >> 8, n = r & 255;
    const float* src; ushort_t* dst; int col;
    switch (s) {
        case 0: src = Wl + 0 * per; dst = ct; col = n;        break;
        case 1: src = Wr + 1 * per; dst = ct; col = 256 + n;  break;
        case 2: src = Wr + 0 * per; dst = cc; col = n;        break;
        case 3: src = Wl + 1 * per; dst = cc; col = 256 + n;  break;
        case 4: src = Wl + 2 * per; dst = cc; col = 512 + n;  break;
        case 5: src = Wr + 3 * per; dst = cc; col = 768 + n;  break;
        case 6: src = Wr + 2 * per; dst = cf; col = n;        break;
        default: src = Wl + 3 * per; dst = cf; col = 256 + n; break;
    }
    dst[(size_t)col * K + k] = f2h(src[(size_t)k * 256 + n]);
}

// out_w [3][256][256] -> owt [3][n=256][k=256]
__global__ void pack_out_k(const float* __restrict__ W, ushort_t* __restrict__ Wt) {
    int i = blockIdx.x * 256 + threadIdx.x;
    if (i >= 3 * 65536) return;
    int t = i >> 16, r = i & 65535;
    int k = r >> 8, n = r & 255;
    Wt[(size_t)t * 65536 + n * 256 + k] = f2h(W[(size_t)t * 65536 + k * 256 + n]);
}

// lin_w [3][256][64] -> lint [3][n=64][k=256]
__global__ void pack_lin_k(const float* __restrict__ W, ushort_t* __restrict__ Wt) {
    int i = blockIdx.x * 256 + threadIdx.x;
    if (i >= 3 * 16384) return;
    int t = i >> 14, r = i & 16383;
    int k = r >> 6, n = r & 63;
    Wt[(size_t)t * 16384 + n * 256 + k] = f2h(W[(size_t)t * 16384 + k * 64 + n]);
}

// ---------- MFMA GEMM: C[M,N] = A[M,K](fp16) @ Wt[N,K](fp16) + bias ----------
// 128x128 tile, BK=32; 4 waves 2x2, each 64x64 via 4x4 16x16x32_f16 frags.
// CT: 0 = fp32 out, 1 = fp16 out. LDS [128][32] fp16, 16B-slot XOR swizzle.
template<int CT>
__global__ __launch_bounds__(256) void gemm_mfma_k(
    const ushort_t* __restrict__ A, const ushort_t* __restrict__ Wt,
    const float* __restrict__ bias, void* __restrict__ Cv,
    int M, int N, int K)
{
    __shared__ __align__(16) ushort_t As[128][32];
    __shared__ __align__(16) ushort_t Bs[128][32];
    const int t = threadIdx.x;
    const int lane = t & 63;
    const int w = t >> 6;
    const int wr = (w >> 1) * 64, wc = (w & 1) * 64;
    const int m0 = blockIdx.x * 128;
    const int n0 = blockIdx.y * 128;
    const int lm = lane & 15, g = lane >> 4;

    f32x4 acc[4][4];
#pragma unroll
    for (int mi = 0; mi < 4; mi++)
#pragma unroll
        for (int ni = 0; ni < 4; ni++) acc[mi][ni] = (f32x4){0.f, 0.f, 0.f, 0.f};

    const int sr = t >> 1;          // staging row 0..127
    const int ss = (t & 1) * 2;     // slots {0,1} or {2,3}
    const int sw = (sr >> 1) & 3;   // swizzle for this staging row

    for (int k0 = 0; k0 < K; k0 += 32) {
        {
            int row = m0 + sr;
            uint4 q0 = make_uint4(0u, 0u, 0u, 0u), q1 = q0;
            if (row < M) {
                const uint4* p = reinterpret_cast<const uint4*>(
                    A + (size_t)row * K + k0 + ss * 8);
                q0 = p[0]; q1 = p[1];
            }
            *reinterpret_cast<uint4*>(&As[sr][((ss + 0) ^ sw) * 8]) = q0;
            *reinterpret_cast<uint4*>(&As[sr][((ss + 1) ^ sw) * 8]) = q1;
        }
        {
            const uint4* p = reinterpret_cast<const uint4*>(
                Wt + (size_t)(n0 + sr) * K + k0 + ss * 8);
            uint4 q0 = p[0], q1 = p[1];
            *reinterpret_cast<uint4*>(&Bs[sr][((ss + 0) ^ sw) * 8]) = q0;
            *reinterpret_cast<uint4*>(&Bs[sr][((ss + 1) ^ sw) * 8]) = q1;
        }
        __syncthreads();
        half8 af[4], bf[4];
#pragma unroll
        for (int mi = 0; mi < 4; mi++) {
            int row = wr + mi * 16 + lm;
            af[mi] = *reinterpret_cast<const half8*>(
                &As[row][(g ^ ((row >> 1) & 3)) * 8]);
        }
#pragma unroll
        for (int ni = 0; ni < 4; ni++) {
            int row = wc + ni * 16 + lm;
            bf[ni] = *reinterpret_cast<const half8*>(
                &Bs[row][(g ^ ((row >> 1) & 3)) * 8]);
        }
#pragma unroll
        for (int mi = 0; mi < 4; mi++)
#pragma unroll
            for (int ni = 0; ni < 4; ni++)
                acc[mi][ni] = __builtin_amdgcn_mfma_f32_16x16x32_f16(
                    af[mi], bf[ni], acc[mi][ni], 0, 0, 0);
        __syncthreads();
    }

    // epilogue: C/D layout col = lane&15, row = (lane>>4)*4 + j  [m89-verified]
#pragma unroll
    for (int mi = 0; mi < 4; mi++) {
#pragma unroll
        for (int j = 0; j < 4; j++) {
            int row = m0 + wr + mi * 16 + g * 4 + j;
            if (row >= M) continue;
#pragma unroll
            for (int ni = 0; ni < 4; ni++) {
                int col = n0 + wc + ni * 16 + lm;
                float v = acc[mi][ni][j];
                if (bias) v += bias[col];
                v = finclamp(v);
                if (CT == 0) {
                    ((float*)Cv)[(size_t)row * N + col] = v;
                } else {
                    ((ushort_t*)Cv)[(size_t)row * N + col] = f2h(v);
                }
            }
        }
    }
}

// ---------- MFMA input projection: C[M,64] = leaky(A_f32[M,K] @ Wt[64,K] + b) ----------
// 128x64 tile; 4 waves stacked in M (32 rows each), fp32->fp16 cvt fused in staging.
__global__ __launch_bounds__(256) void gemm_in_k(
    const float* __restrict__ A, const ushort_t* __restrict__ Wt,
    const float* __restrict__ bias, ushort_t* __restrict__ C, int M, int K)
{
    __shared__ __align__(16) ushort_t As[128][32];
    __shared__ __align__(16) ushort_t Bs[64][32];
    const int t = threadIdx.x;
    const int lane = t & 63;
    const int w = t >> 6;
    const int m0 = blockIdx.x * 128;
    const int lm = lane & 15, g = lane >> 4;

    f32x4 acc[2][4];
#pragma unroll
    for (int mi = 0; mi < 2; mi++)
#pragma unroll
        for (int ni = 0; ni < 4; ni++) acc[mi][ni] = (f32x4){0.f, 0.f, 0.f, 0.f};

    const int sr = t >> 1;
    const int ss = (t & 1) * 2;
    const int sw = (sr >> 1) & 3;
    const int br = t >> 2;          // B staging row 0..63
    const int bs = t & 3;           // B slot
    const int bw = (br >> 1) & 3;

    for (int k0 = 0; k0 < K; k0 += 32) {
        {
            int row = m0 + sr;
            U16x8 a, b;
            if (row < M) {
                const float4* p = reinterpret_cast<const float4*>(
                    A + (size_t)row * K + k0 + (t & 1) * 16);
                float4 q0 = p[0], q1 = p[1], q2 = p[2], q3 = p[3];
                a.u[0] = f2h(q0.x); a.u[1] = f2h(q0.y); a.u[2] = f2h(q0.z); a.u[3] = f2h(q0.w);
                a.u[4] = f2h(q1.x); a.u[5] = f2h(q1.y); a.u[6] = f2h(q1.z); a.u[7] = f2h(q1.w);
                b.u[0] = f2h(q2.x); b.u[1] = f2h(q2.y); b.u[2] = f2h(q2.z); b.u[3] = f2h(q2.w);
                b.u[4] = f2h(q3.x); b.u[5] = f2h(q3.y); b.u[6] = f2h(q3.z); b.u[7] = f2h(q3.w);
            } else {
                a.q = make_uint4(0u, 0u, 0u, 0u); b.q = a.q;
            }
            *reinterpret_cast<uint4*>(&As[sr][((ss + 0) ^ sw) * 8]) = a.q;
            *reinterpret_cast<uint4*>(&As[sr][((ss + 1) ^ sw) * 8]) = b.q;
        }
        {
            uint4 q = *reinterpret_cast<const uint4*>(
                Wt + (size_t)br * K + k0 + bs * 8);
            *reinterpret_cast<uint4*>(&Bs[br][(bs ^ bw) * 8]) = q;
        }
        __syncthreads();
        half8 af[2], bf[4];
#pragma unroll
        for (int mi = 0; mi < 2; mi++) {
            int row = w * 32 + mi * 16 + lm;
            af[mi] = *reinterpret_cast<const half8*>(
                &As[row][(g ^ ((row >> 1) & 3)) * 8]);
        }
#pragma unroll
        for (int ni = 0; ni < 4; ni++) {
            int row = ni * 16 + lm;
            bf[ni] = *reinterpret_cast<const half8*>(
                &Bs[row][(g ^ ((row >> 1) & 3)) * 8]);
        }
#pragma unroll
        for (int mi = 0; mi < 2; mi++)
#pragma unroll
            for (int ni = 0; ni < 4; ni++)
                acc[mi][ni] = __builtin_amdgcn_mfma_f32_16x16x32_f16(
                    af[mi], bf[ni], acc[mi][ni], 0, 0, 0);
        __syncthreads();
    }

#pragma unroll
    for (int mi = 0; mi < 2; mi++) {
#pragma unroll
        for (int j = 0; j < 4; j++) {
            int row = m0 + w * 32 + mi * 16 + g * 4 + j;
            if (row >= M) continue;
#pragma unroll
            for (int ni = 0; ni < 4; ni++) {
                int col = ni * 16 + lm;
                float v = acc[mi][ni][j] + bias[col];
                v = (v > 0.f) ? v : 0.01f * v;
                C[(size_t)row * 64 + col] = f2h(finclamp(v));
            }
        }
    }
}

// ---------- CSR build: counting sort of edges by dst ----------
__global__ void zero2_k(int* __restrict__ a, int* __restrict__ b, int n) {
    int i = blockIdx.x * 256 + threadIdx.x;
    if (i < n) { a[i] = 0; b[i] = 0; }
}

__global__ void hist_k(const int* __restrict__ dst, int* __restrict__ cnt, int E) {
    int e = blockIdx.x * 256 + threadIdx.x;
    if (e < E) atomicAdd(&cnt[dst[e]], 1);
}

// parallel 3-phase exclusive scan: per-block scan -> 1-wave top scan -> fixup
__global__ __launch_bounds__(1024) void scan_blk_k(const int* __restrict__ cnt,
                                                   int* __restrict__ off,
                                                   int* __restrict__ bsum, int n) {
    __shared__ int wsum[16];
    int t = threadIdx.x, lane = t & 63, w = t >> 6;
    int i = blockIdx.x * 4096 + t * 4;
    int v[4];
#pragma unroll
    for (int k = 0; k < 4; k++) v[k] = (i + k < n) ? cnt[i + k] : 0;
    int ts = v[0] + v[1] + v[2] + v[3];
    int x = ts;
#pragma unroll
    for (int sh = 1; sh < 64; sh <<= 1) {
        int y = __shfl_up(x, sh);
        if (lane >= sh) x += y;
    }
    if (lane == 63) wsum[w] = x;
    __syncthreads();
    int wbase = 0;
    for (int k = 0; k < w; k++) wbase += wsum[k];
    int excl = wbase + (x - ts);
#pragma unroll
    for (int k = 0; k < 4; k++) {
        if (i + k < n) off[i + k] = excl;
        excl += v[k];
    }
    if (t == 1023) bsum[blockIdx.x] = wbase + x;   // block total
}

__global__ void scan_top_k(int* __restrict__ bsum, int* __restrict__ off,
                           int n, int nb) {
    int lane = threadIdx.x;
    int v = (lane < nb) ? bsum[lane] : 0;
    int x = v;
#pragma unroll
    for (int sh = 1; sh < 64; sh <<= 1) {
        int y = __shfl_up(x, sh);
        if (lane >= sh) x += y;
    }
    if (lane < nb) bsum[lane] = x - v;
    if (lane == 63) off[n] = x;
}

__global__ void scan_fix_k(int* __restrict__ off, const int* __restrict__ bsum, int n) {
    int i = blockIdx.x * 256 + threadIdx.x;
    if (i < n) off[i] += bsum[i >> 12];
}

__global__ void permsrc_k(const int* __restrict__ dst, const int* __restrict__ src,
                          const int* __restrict__ off, int* __restrict__ cur,
                          int* __restrict__ ssrc, int E) {
    int e = blockIdx.x * 256 + threadIdx.x;
    if (e >= E) return;
    int d = dst[e];
    int slot = atomicAdd(&cur[d], 1);
    ssrc[off[d] + slot] = src[e];
}

// ---------- fused GATv2 gather + bias + ELU + fp16 store ----------
// One wave per dst node; lane owns features f..f+3. Online softmax per edge type.
__device__ __forceinline__ void gat_accum(
    const ushort_t* __restrict__ xl, int ldl,
    const ushort_t* __restrict__ xr, int ldr,
    const float* __restrict__ att, const int* __restrict__ off,
    const int* __restrict__ ssrc, int d, int f,
    float& o0, float& o1, float& o2, float& o3)
{
    int j0 = off[d], j1 = off[d + 1];
    if (j0 == j1) return;                       // empty segment: msg = 0
    float4 qa = *reinterpret_cast<const float4*>(att + f);
    uint2 qr = *reinterpret_cast<const uint2*>(xr + (size_t)d * ldr + f);
    float r0 = hlo(qr.x), r1 = hhi(qr.x), r2 = hlo(qr.y), r3 = hhi(qr.y);
    float m = -1e30f, den = 0.f;
    float a0 = 0.f, a1 = 0.f, a2 = 0.f, a3 = 0.f;
    for (int j = j0; j < j1; ++j) {
        int s = ssrc[j];
        uint2 ql = *reinterpret_cast<const uint2*>(xl + (size_t)s * ldl + f);
        float l0 = hlo(ql.x), l1 = hhi(ql.x), l2 = hlo(ql.y), l3 = hhi(ql.y);
        float v0 = l0 + r0, v1 = l1 + r1, v2 = l2 + r2, v3 = l3 + r3;
        v0 = (v0 > 0.f) ? v0 : 0.2f * v0;
        v1 = (v1 > 0.f) ? v1 : 0.2f * v1;
        v2 = (v2 > 0.f) ? v2 : 0.2f * v2;
        v3 = (v3 > 0.f) ? v3 : 0.2f * v3;
        float lg = qa.x * v0 + qa.y * v1 + qa.z * v2 + qa.w * v3;
        lg += __shfl_xor(lg, 1);
        lg += __shfl_xor(lg, 2);
        lg += __shfl_xor(lg, 4);
        lg += __shfl_xor(lg, 8);
        float mn = fmaxf(m, lg);
        float sc = expf(m - mn);
        float z  = expf(lg - mn);
        den = den * sc + z;
        a0 = a0 * sc + z * l0;
        a1 = a1 * sc + z * l1;
        a2 = a2 * sc + z * l2;
        a3 = a3 * sc + z * l3;
        m = mn;
    }
    float inv = (den > 0.f) ? 1.f / den : 0.f;
    o0 += finclamp(a0 * inv);
    o1 += finclamp(a1 * inv);
    o2 += finclamp(a2 * inv);
    o3 += finclamp(a3 * inv);
}

__global__ __launch_bounds__(256) void gat_gather2_k(
    const ushort_t* __restrict__ xl1, int ldl1,
    const ushort_t* __restrict__ xr1, int ldr1,
    const float* __restrict__ att1, const int* __restrict__ off1,
    const int* __restrict__ ssrc1,
    const ushort_t* __restrict__ xl2, int ldl2,
    const ushort_t* __restrict__ xr2, int ldr2,
    const float* __restrict__ att2, const int* __restrict__ off2,
    const int* __restrict__ ssrc2,
    const float* __restrict__ b1, const float* __restrict__ b2,
    float scale, ushort_t* __restrict__ xout, int Nd)
{
    int d = blockIdx.x * 4 + (threadIdx.x >> 6);
    if (d >= Nd) return;
    int lane = threadIdx.x & 63;
    int f = lane * 4;
    float o0 = 0.f, o1 = 0.f, o2 = 0.f, o3 = 0.f;
    gat_accum(xl1, ldl1, xr1, ldr1, att1, off1, ssrc1, d, f, o0, o1, o2, o3);
    if (off2) gat_accum(xl2, ldl2, xr2, ldr2, att2, off2, ssrc2, d, f, o0, o1, o2, o3);
    float4 bv = *reinterpret_cast<const float4*>(b1 + f);
    o0 += bv.x; o1 += bv.y; o2 += bv.z; o3 += bv.w;
    if (b2) {
        float4 b2v = *reinterpret_cast<const float4*>(b2 + f);
        o0 += b2v.x; o1 += b2v.y; o2 += b2v.z; o3 += b2v.w;
    }
    o0 *= scale; o1 *= scale; o2 *= scale; o3 *= scale;
    o0 = (o0 > 0.f) ? o0 : (expf(o0) - 1.f);
    o1 = (o1 > 0.f) ? o1 : (expf(o1) - 1.f);
    o2 = (o2 > 0.f) ? o2 : (expf(o2) - 1.f);
    o3 = (o3 > 0.f) ? o3 : (expf(o3) - 1.f);
    uint32 lo = ((uint32)f2h(finclamp(o1)) << 16) | (uint32)f2h(finclamp(o0));
    uint32 hi = ((uint32)f2h(finclamp(o3)) << 16) | (uint32)f2h(finclamp(o2));
    *reinterpret_cast<uint2*>(xout + (size_t)d * FDIM + f) = make_uint2(lo, hi);
}

// ---------- host launch ----------
extern "C" void kernel_launch(void* const* d_in, const int* in_sizes, int n_in,
                              void* d_out, int out_size, void* d_ws, size_t ws_size,
                              hipStream_t stream) {
    (void)in_sizes; (void)n_in; (void)out_size;
    const float* x_table = (const float*)d_in[0];
    const float* x_column = (const float*)d_in[1];
    const float* x_fk = (const float*)d_in[2];
    const float* lin_w = (const float*)d_in[3];   // [3,256,64]
    const float* lin_b = (const float*)d_in[4];   // [3,64]
    const float* out_w = (const float*)d_in[5];   // [3,256,256]
    const float* out_b = (const float*)d_in[6];   // [3,256]
    const float* Wl0 = (const float*)d_in[7];     // [4,64,256]
    const float* Wr0 = (const float*)d_in[8];
    const float* att0 = (const float*)d_in[9];    // [4,4,64]
    const float* b0 = (const float*)d_in[10];     // [4,256]
    const float* Wl1 = (const float*)d_in[11];    // [4,256,256]
    const float* Wr1 = (const float*)d_in[12];
    const float* att1 = (const float*)d_in[13];
    const float* b1 = (const float*)d_in[14];
    const int* src_hc = (const int*)d_in[15];
    const int* dst_hc = (const int*)d_in[16];
    const int* src_bt = (const int*)d_in[17];
    const int* dst_bt = (const int*)d_in[18];
    const int* src_is = (const int*)d_in[19];
    const int* dst_is = (const int*)d_in[20];
    const int* src_pt = (const int*)d_in[21];
    const int* dst_pt = (const int*)d_in[22];
    float* out = (float*)d_out;

    // ---- carve workspace (~607 MB) ----
    char* p = (char*)d_ws;
    auto alloc = [&](size_t bytes) -> char* {
        char* r = p;
        p += (bytes + 255) & ~(size_t)255;
        return r;
    };
    ushort_t* xt = (ushort_t*)alloc((size_t)NT * FDIM * 2);
    ushort_t* xc = (ushort_t*)alloc((size_t)NC * FDIM * 2);
    ushort_t* xf = (ushort_t*)alloc((size_t)NF * FDIM * 2);
    // per-node-type concatenated projection buffers
    ushort_t* pt_buf = (ushort_t*)alloc((size_t)NT * 512 * 2);
    ushort_t* pc_buf = (ushort_t*)alloc((size_t)NC * 1024 * 2);
    ushort_t* pf_buf = (ushort_t*)alloc((size_t)NF * 512 * 2);
    int* off_hc = (int*)alloc((size_t)(NC + 1) * 4);
    int* off_bt = (int*)alloc((size_t)(NT + 1) * 4);
    int* off_is = (int*)alloc((size_t)(NF + 1) * 4);
    int* off_pt = (int*)alloc((size_t)(NC + 1) * 4);
    int* ssrc_hc = (int*)alloc((size_t)E_HC * 4);
    int* ssrc_bt = (int*)alloc((size_t)E_BT * 4);
    int* ssrc_is = (int*)alloc((size_t)E_IS * 4);
    int* ssrc_pt = (int*)alloc((size_t)E_PT * 4);
    int* cnt = (int*)alloc((size_t)NC * 4);
    int* cur = (int*)alloc((size_t)NC * 4);
    int* bsum = (int*)alloc((size_t)64 * 4);
    // packed fp16 weights (transposed [N][K])
    ushort_t* wcat_t0 = (ushort_t*)alloc((size_t)512 * 64 * 2);
    ushort_t* wcat_c0 = (ushort_t*)alloc((size_t)1024 * 64 * 2);
    ushort_t* wcat_f0 = (ushort_t*)alloc((size_t)512 * 64 * 2);
    ushort_t* wcat_t1 = (ushort_t*)alloc((size_t)512 * 256 * 2);
    ushort_t* wcat_c1 = (ushort_t*)alloc((size_t)1024 * 256 * 2);
    ushort_t* wcat_f1 = (ushort_t*)alloc((size_t)512 * 256 * 2);
    ushort_t* owt = (ushort_t*)alloc((size_t)3 * 65536 * 2);
    ushort_t* lint = (ushort_t*)alloc((size_t)3 * 16384 * 2);
    if ((size_t)(p - (char*)d_ws) > ws_size) return;

    // ---- weight packs (once) ----
    hipLaunchKernelGGL(pack_layer_k, dim3((8 * 64 * 256 + 255) / 256), dim3(256), 0,
                       stream, Wl0, Wr0, wcat_t0, wcat_c0, wcat_f0, 64);
    hipLaunchKernelGGL(pack_layer_k, dim3((8 * 256 * 256 + 255) / 256), dim3(256), 0,
                       stream, Wl1, Wr1, wcat_t1, wcat_c1, wcat_f1, 256);
    hipLaunchKernelGGL(pack_out_k, dim3((3 * 65536 + 255) / 256), dim3(256), 0,
                       stream, out_w, owt);
    hipLaunchKernelGGL(pack_lin_k, dim3((3 * 16384 + 255) / 256), dim3(256), 0,
                       stream, lin_w, lint);

    // ---- CSR build (once; reused by both layers) ----
    auto build_csr = [&](const int* dst, const int* src, int E, int Nd,
                         int* off, int* ssrc) {
        int nb = (Nd + 4095) / 4096;
        hipLaunchKernelGGL(zero2_k, dim3((Nd + 255) / 256), dim3(256), 0, stream,
                           cnt, cur, Nd);
        hipLaunchKernelGGL(hist_k, dim3((E + 255) / 256), dim3(256), 0, stream,
                           dst, cnt, E);
        hipLaunchKernelGGL(scan_blk_k, dim3(nb), dim3(1024), 0, stream,
                           cnt, off, bsum, Nd);
        hipLaunchKernelGGL(scan_top_k, dim3(1), dim3(64), 0, stream,
                           bsum, off, Nd, nb);
        hipLaunchKernelGGL(scan_fix_k, dim3((Nd + 255) / 256), dim3(256), 0, stream,
                           off, bsum, Nd);
        hipLaunchKernelGGL(permsrc_k, dim3((E + 255) / 256), dim3(256), 0, stream,
                           dst, src, off, cur, ssrc, E);
    };
    build_csr(dst_hc, src_hc, E_HC, NC, off_hc, ssrc_hc);
    build_csr(dst_bt, src_bt, E_BT, NT, off_bt, ssrc_bt);
    build_csr(dst_is, src_is, E_IS, NF, off_is, ssrc_is);
    build_csr(dst_pt, src_pt, E_PT, NC, off_pt, ssrc_pt);

    // ---- input projections: MFMA with fused fp32->fp16 cvt, N=64 ----
    hipLaunchKernelGGL(gemm_in_k, dim3((NT + 127) / 128), dim3(256), 0, stream,
                       x_table, lint + 0 * 16384, lin_b + 0 * 64, xt, NT, 256);
    hipLaunchKernelGGL(gemm_in_k, dim3((NC + 127) / 128), dim3(256), 0, stream,
                       x_column, lint + 1 * 16384, lin_b + 1 * 64, xc, NC, 256);
    hipLaunchKernelGGL(gemm_in_k, dim3((NF + 127) / 128), dim3(256), 0, stream,
                       x_fk, lint + 2 * 16384, lin_b + 2 * 64, xf, NF, 256);

    auto gemm_cat = [&](const ushort_t* A, const ushort_t* Wt, ushort_t* C,
                        int M, int N, int K) {
        hipLaunchKernelGGL((gemm_mfma_k<1>), dim3((M + 127) / 128, N / 128),
                           dim3(256), 0, stream, A, Wt, (const float*)nullptr,
                           (void*)C, M, N, K);
    };

    for (int l = 0; l < 2; l++) {
        const ushort_t* wt_t = l ? wcat_t1 : wcat_t0;
        const ushort_t* wt_c = l ? wcat_c1 : wcat_c0;
        const ushort_t* wt_f = l ? wcat_f1 : wcat_f0;
        const float* att = l ? att1 : att0;
        const float* bb = l ? b1 : b0;
        int Kd = l ? 256 : 64;

        // concatenated projections (xt/xc/xf fully consumed before gathers overwrite)
        gemm_cat(xt, wt_t, pt_buf, NT, 512, Kd);
        gemm_cat(xc, wt_c, pc_buf, NC, 1024, Kd);
        gemm_cat(xf, wt_f, pf_buf, NF, 512, Kd);

        // fused gathers: bias + softmax-msg(s) + ELU -> fp16 next-layer feats
        // bt -> xt
        hipLaunchKernelGGL(gat_gather2_k, dim3((NT + 3) / 4), dim3(256), 0, stream,
                           pc_buf + 256, 1024, pt_buf + 256, 512,
                           att + 1 * FDIM, off_bt, ssrc_bt,
                           (const ushort_t*)nullptr, 0, (const ushort_t*)nullptr, 0,
                           (const float*)nullptr, (const int*)nullptr,
                           (const int*)nullptr,
                           bb + 1 * FDIM, (const float*)nullptr, 1.0f, xt, NT);
        // is -> xf
        hipLaunchKernelGGL(gat_gather2_k, dim3((NF + 3) / 4), dim3(256), 0, stream,
                           pc_buf + 512, 1024, pf_buf + 0, 512,
                           att + 2 * FDIM, off_is, ssrc_is,
                           (const ushort_t*)nullptr, 0, (const ushort_t*)nullptr, 0,
                           (const float*)nullptr, (const int*)nullptr,
                           (const int*)nullptr,
                           bb + 2 * FDIM, (const float*)nullptr, 1.0f, xf, NF);
        // hc + pt -> xc (mean of the two types)
        hipLaunchKernelGGL(gat_gather2_k, dim3((NC + 3) / 4), dim3(256), 0, stream,
                           pt_buf + 0, 512, pc_buf + 0, 1024,
                           att + 0 * FDIM, off_hc, ssrc_hc,
                           pf_buf + 256, 512, pc_buf + 768, 1024,
                           att + 3 * FDIM, off_pt, ssrc_pt,
                           bb + 0 * FDIM, bb + 3 * FDIM, 0.5f, xc, NC);
    }

    // ---- output projections -> d_out (concat xt, xc, xf), fp32 ----
    hipLaunchKernelGGL((gemm_mfma_k<0>), dim3((NT + 127) / 128, 2), dim3(256), 0,
                       stream, xt, owt + 0 * 65536, out_b + 0 * 256,
                       (void*)out, NT, 256, 256);
    hipLaunchKernelGGL((gemm_mfma_k<0>), dim3((NC + 127) / 128, 2), dim3(256), 0,
                       stream, xc, owt + 1 * 65536, out_b + 1 * 256,
                       (void*)(out + (size_t)NT * FDIM), NC, 256, 256);
    hipLaunchKernelGGL((gemm_mfma_k<0>), dim3((NF + 127) / 128, 2), dim3(256), 0,
                       stream, xf, owt + 2 * 65536, out_b + 2 * 256,
                       (void*)(out + (size_t)(NT + NC) * FDIM), NF, 256, 256);
}